// Round 2
// baseline (593.677 us; speedup 1.0000x reference)
//
#include <hip/hip_runtime.h>
#include <hip/hip_bf16.h>

#define BB 4
#define LL 2048
#define DD 512
#define DKK 256
#define BM 32
#define BN 64

typedef __bf16 bf16;
typedef __bf16 bf16x8 __attribute__((ext_vector_type(8)));
typedef float f32x4 __attribute__((ext_vector_type(4)));

__device__ inline bf16x8 ld_a_f32(const float* p) {
    f32x4 lo = *(const f32x4*)p;
    f32x4 hi = *(const f32x4*)(p + 4);
    bf16x8 r;
    #pragma unroll
    for (int j = 0; j < 4; ++j) { r[j] = (bf16)lo[j]; r[j + 4] = (bf16)hi[j]; }
    return r;
}

__global__ void transpose_f32_bf16(const float* __restrict__ in, bf16* __restrict__ out,
                                   int R, int C) {
    int idx = blockIdx.x * 256 + threadIdx.x;
    if (idx < R * C) {
        int r = idx / C, c = idx % C;
        out[(size_t)c * R + r] = (bf16)in[idx];
    }
}

__global__ void convert_f32_bf16(const float* __restrict__ in, bf16* __restrict__ out, int n) {
    int idx = blockIdx.x * 256 + threadIdx.x;
    if (idx < n) out[idx] = (bf16)in[idx];
}

// C[m][n] = sum_k A[m][k] * Bt[n][k].  64x64 block tile, 4 waves, each wave 32x32.
// AF32: A operand is float32, converted to bf16 in-register.
template <int AF32>
__global__ void gemm_bt(const void* __restrict__ Av, const bf16* __restrict__ Bt,
                        bf16* __restrict__ C, int M, int N, int K,
                        long aStride, long cStride, int transStore, int ldct)
{
    int tid  = threadIdx.x;
    int lane = tid & 63;
    int wid  = tid >> 6;
    int l15  = lane & 15;
    int quad = lane >> 4;
    int nb = N >> 6;
    int gx = blockIdx.x % nb;
    int gy = blockIdx.x / nb;
    int m0 = gy * 64 + (wid & 1) * 32;
    int n0 = gx * 64 + (wid >> 1) * 32;

    f32x4 acc00 = 0, acc01 = 0, acc10 = 0, acc11 = 0;
    const bf16* br0 = Bt + (size_t)(n0 + l15) * K + quad * 8;
    const bf16* br1 = br0 + (size_t)16 * K;

    if (AF32) {
        const float* Ab  = (const float*)Av + (size_t)blockIdx.y * aStride;
        const float* ar0 = Ab + (size_t)(m0 + l15) * K + quad * 8;
        const float* ar1 = ar0 + (size_t)16 * K;
        for (int k0 = 0; k0 < K; k0 += 32) {
            bf16x8 a0 = ld_a_f32(ar0 + k0);
            bf16x8 a1 = ld_a_f32(ar1 + k0);
            bf16x8 b0 = *(const bf16x8*)(br0 + k0);
            bf16x8 b1 = *(const bf16x8*)(br1 + k0);
            acc00 = __builtin_amdgcn_mfma_f32_16x16x32_bf16(a0, b0, acc00, 0, 0, 0);
            acc01 = __builtin_amdgcn_mfma_f32_16x16x32_bf16(a0, b1, acc01, 0, 0, 0);
            acc10 = __builtin_amdgcn_mfma_f32_16x16x32_bf16(a1, b0, acc10, 0, 0, 0);
            acc11 = __builtin_amdgcn_mfma_f32_16x16x32_bf16(a1, b1, acc11, 0, 0, 0);
        }
    } else {
        const bf16* Ab  = (const bf16*)Av + (size_t)blockIdx.y * aStride;
        const bf16* ar0 = Ab + (size_t)(m0 + l15) * K + quad * 8;
        const bf16* ar1 = ar0 + (size_t)16 * K;
        for (int k0 = 0; k0 < K; k0 += 32) {
            bf16x8 a0 = *(const bf16x8*)(ar0 + k0);
            bf16x8 a1 = *(const bf16x8*)(ar1 + k0);
            bf16x8 b0 = *(const bf16x8*)(br0 + k0);
            bf16x8 b1 = *(const bf16x8*)(br1 + k0);
            acc00 = __builtin_amdgcn_mfma_f32_16x16x32_bf16(a0, b0, acc00, 0, 0, 0);
            acc01 = __builtin_amdgcn_mfma_f32_16x16x32_bf16(a0, b1, acc01, 0, 0, 0);
            acc10 = __builtin_amdgcn_mfma_f32_16x16x32_bf16(a1, b0, acc10, 0, 0, 0);
            acc11 = __builtin_amdgcn_mfma_f32_16x16x32_bf16(a1, b1, acc11, 0, 0, 0);
        }
    }

    bf16* Cb = C + (size_t)blockIdx.y * cStride;
    #pragma unroll
    for (int t = 0; t < 4; ++t) {
        f32x4 av = (t == 0) ? acc00 : (t == 1) ? acc01 : (t == 2) ? acc10 : acc11;
        int ti = t >> 1, tj = t & 1;
        #pragma unroll
        for (int r = 0; r < 4; ++r) {
            int m = m0 + ti * 16 + quad * 4 + r;
            int n = n0 + tj * 16 + l15;
            bf16 v = (bf16)av[r];
            if (!transStore) Cb[(size_t)m * N + n] = v;
            else             Cb[(size_t)n * ldct + m] = v;
        }
    }
}

// Fused attention: per (batch, 32-row Q tile).  S=QK^T + skew(QE), online softmax, O=P·V.
__launch_bounds__(256)
__global__ void attn_kernel(const bf16* __restrict__ Qw, const bf16* __restrict__ Kw,
                            const bf16* __restrict__ Vt, const bf16* __restrict__ QE,
                            float* __restrict__ out)
{
    __shared__ bf16  Qs[BM][264];
    __shared__ float Ss[BM][68];
    __shared__ bf16  Ps[BM][72];
    __shared__ float mSt[BM], lSt[BM], aSt[BM];

    int tid  = threadIdx.x;
    int lane = tid & 63;
    int wid  = tid >> 6;
    int l15  = lane & 15;
    int quad = lane >> 4;

    int b  = blockIdx.x >> 6;
    int i0 = (blockIdx.x & 63) * BM;

    const bf16* Qb  = Qw + ((size_t)b * LL) * DKK;
    const bf16* Kb  = Kw + ((size_t)b * LL) * DKK;
    const bf16* QEb = QE + (size_t)b * LL * LL;

    {   // stage Q tile [32][256] into LDS
        int row = tid >> 3, sg = tid & 7;
        const bf16* src = Qb + (size_t)(i0 + row) * DKK + sg * 32;
        #pragma unroll
        for (int u = 0; u < 4; ++u)
            *(bf16x8*)&Qs[row][sg * 32 + u * 8] = *(const bf16x8*)(src + u * 8);
    }
    if (tid < BM) { mSt[tid] = -1e30f; lSt[tid] = 0.f; }
    __syncthreads();

    int ti  = wid & 1;
    int tjp = wid >> 1;
    int d0  = (wid >> 1) * 256;

    f32x4 accO[16];
    #pragma unroll
    for (int t = 0; t < 16; ++t) accO[t] = 0;

    for (int j0 = 0; j0 < LL; j0 += BN) {
        // ---- S = Q·K^T
        f32x4 s0 = 0, s1 = 0;
        const bf16* k0p = Kb + (size_t)(j0 + tjp * 32 + l15) * DKK + quad * 8;
        const bf16* k1p = k0p + (size_t)16 * DKK;
        #pragma unroll
        for (int ks = 0; ks < 8; ++ks) {
            bf16x8 a  = *(const bf16x8*)&Qs[ti * 16 + l15][ks * 32 + quad * 8];
            bf16x8 b0 = *(const bf16x8*)(k0p + ks * 32);
            bf16x8 b1 = *(const bf16x8*)(k1p + ks * 32);
            s0 = __builtin_amdgcn_mfma_f32_16x16x32_bf16(a, b0, s0, 0, 0, 0);
            s1 = __builtin_amdgcn_mfma_f32_16x16x32_bf16(a, b1, s1, 0, 0, 0);
        }
        // ---- add skewed relative logits: Srel[i][j] = j<=i ? QE[i][L-1-i+j]
        //      : (j==i+1 ? 0 : QE[i+1][j-i-2])
        #pragma unroll
        for (int t = 0; t < 2; ++t) {
            f32x4 s = t ? s1 : s0;
            int jc = j0 + tjp * 32 + t * 16 + l15;
            #pragma unroll
            for (int r = 0; r < 4; ++r) {
                int il = ti * 16 + quad * 4 + r;
                int i  = i0 + il;
                float srel = 0.f;
                if (jc <= i)         srel = (float)QEb[(size_t)i * LL + (LL - 1 - i + jc)];
                else if (jc > i + 1) srel = (float)QEb[(size_t)(i + 1) * LL + (jc - i - 2)];
                Ss[il][tjp * 32 + t * 16 + l15] = (s[r] + srel) * 0.0625f;
            }
        }
        __syncthreads();
        // ---- online softmax: 8 threads per row
        {
            int r = tid >> 3, sg = tid & 7;
            float v[8];
            #pragma unroll
            for (int c = 0; c < 8; ++c) v[c] = Ss[r][sg * 8 + c];
            float tmax = v[0];
            #pragma unroll
            for (int c = 1; c < 8; ++c) tmax = fmaxf(tmax, v[c]);
            tmax = fmaxf(tmax, __shfl_xor(tmax, 1));
            tmax = fmaxf(tmax, __shfl_xor(tmax, 2));
            tmax = fmaxf(tmax, __shfl_xor(tmax, 4));
            float mOld = mSt[r], lOld = lSt[r];
            float mNew = fmaxf(mOld, tmax);
            float alpha = __expf(mOld - mNew);
            float ps = 0.f;
            bf16x8 pv;
            #pragma unroll
            for (int c = 0; c < 8; ++c) {
                float p = __expf(v[c] - mNew);
                ps += p;
                pv[c] = (bf16)p;
            }
            ps += __shfl_xor(ps, 1);
            ps += __shfl_xor(ps, 2);
            ps += __shfl_xor(ps, 4);
            *(bf16x8*)&Ps[r][sg * 8] = pv;
            if (sg == 0) { mSt[r] = mNew; lSt[r] = alpha * lOld + ps; aSt[r] = alpha; }
        }
        __syncthreads();
        // ---- O = alpha*O + P·V
        bf16x8 aF0 = *(const bf16x8*)&Ps[ti * 16 + l15][quad * 8];
        bf16x8 aF1 = *(const bf16x8*)&Ps[ti * 16 + l15][32 + quad * 8];
        float ar[4];
        #pragma unroll
        for (int r = 0; r < 4; ++r) ar[r] = aSt[ti * 16 + quad * 4 + r];
        const bf16* vbase = Vt + (size_t)(d0 + l15) * (BB * LL) + (size_t)b * LL + j0 + quad * 8;
        #pragma unroll 4
        for (int td = 0; td < 16; ++td) {
            const bf16* vp = vbase + (size_t)td * 16 * (BB * LL);
            bf16x8 bF0 = *(const bf16x8*)(vp);
            bf16x8 bF1 = *(const bf16x8*)(vp + 32);
            f32x4 o = accO[td];
            o[0] *= ar[0]; o[1] *= ar[1]; o[2] *= ar[2]; o[3] *= ar[3];
            o = __builtin_amdgcn_mfma_f32_16x16x32_bf16(aF0, bF0, o, 0, 0, 0);
            o = __builtin_amdgcn_mfma_f32_16x16x32_bf16(aF1, bF1, o, 0, 0, 0);
            accO[td] = o;
        }
    }
    // ---- epilogue: divide by l, store f32
    float lr[4];
    #pragma unroll
    for (int r = 0; r < 4; ++r) lr[r] = 1.f / lSt[ti * 16 + quad * 4 + r];
    #pragma unroll 4
    for (int td = 0; td < 16; ++td) {
        #pragma unroll
        for (int r = 0; r < 4; ++r) {
            int i = i0 + ti * 16 + quad * 4 + r;
            int d = d0 + td * 16 + l15;
            out[((size_t)b * LL + i) * DD + d] = accO[td][r] * lr[r];
        }
    }
}

extern "C" void kernel_launch(void* const* d_in, const int* in_sizes, int n_in,
                              void* d_out, int out_size, void* d_ws, size_t ws_size,
                              hipStream_t stream) {
    const float* inQ = (const float*)d_in[0];
    const float* inK = (const float*)d_in[1];
    const float* inV = (const float*)d_in[2];
    const float* Wq  = (const float*)d_in[3];
    const float* Wk  = (const float*)d_in[4];
    const float* Wv  = (const float*)d_in[5];
    const float* E   = (const float*)d_in[6];
    float* out = (float*)d_out;

    char* ws = (char*)d_ws;
    bf16* Qw  = (bf16*)(ws);                         // 4 MB  [B,L,DK]
    bf16* Kw  = (bf16*)(ws + ((size_t)4  << 20));    // 4 MB  [B,L,DK]
    bf16* Vt  = (bf16*)(ws + ((size_t)8  << 20));    // 8 MB  [D, B*L]
    bf16* QEw = (bf16*)(ws + ((size_t)16 << 20));    // 32 MB [B,L,L]
    bf16* WqT = (bf16*)(ws + ((size_t)48 << 20));            // [DK,D]
    bf16* WkT = (bf16*)(ws + ((size_t)48 << 20) + 262144);   // [DK,D]
    bf16* WvT = (bf16*)(ws + ((size_t)48 << 20) + 524288);   // [D,D]
    bf16* Eb  = (bf16*)(ws + ((size_t)49 << 20));            // [L,DK] bf16

    transpose_f32_bf16<<<512,  256, 0, stream>>>(Wq, WqT, DD, DKK);
    transpose_f32_bf16<<<512,  256, 0, stream>>>(Wk, WkT, DD, DKK);
    transpose_f32_bf16<<<1024, 256, 0, stream>>>(Wv, WvT, DD, DD);
    convert_f32_bf16<<<2048, 256, 0, stream>>>(E, Eb, LL * DKK);

    // Q = inQ · Wq   (M=8192, N=256, K=512)
    gemm_bt<1><<<dim3(512, 1),  256, 0, stream>>>(inQ, WqT, Qw, BB*LL, DKK, DD, 0, 0, 0, 0);
    // K = inK · Wk
    gemm_bt<1><<<dim3(512, 1),  256, 0, stream>>>(inK, WkT, Kw, BB*LL, DKK, DD, 0, 0, 0, 0);
    // Vt = (inV · Wv)^T  stored [D][B*L]
    gemm_bt<1><<<dim3(1024, 1), 256, 0, stream>>>(inV, WvT, Vt, BB*LL, DD, DD, 0, 0, 1, BB*LL);
    // QE[b] = Q[b] · E^T  (M=N=2048, K=256), batched over blockIdx.y
    gemm_bt<0><<<dim3(1024, BB), 256, 0, stream>>>(Qw, Eb, QEw, LL, LL, DKK,
                                                   (long)LL*DKK, (long)LL*LL, 0, 0);
    // fused attention
    attn_kernel<<<dim3(BB * (LL / BM)), 256, 0, stream>>>(Qw, Kw, Vt, QEw, out);
}

// Round 3
// 590.039 us; speedup vs baseline: 1.0062x; 1.0062x over previous
//
#include <hip/hip_runtime.h>
#include <hip/hip_bf16.h>

#define BB 4
#define LL 2048
#define DD 512
#define DKK 256
#define BM 32
#define BN 64

typedef __bf16 bf16;
typedef __bf16 bf16x4 __attribute__((ext_vector_type(4)));
typedef __bf16 bf16x8 __attribute__((ext_vector_type(8)));
typedef float f32x4 __attribute__((ext_vector_type(4)));

__device__ inline bf16x8 ld_a_f32(const float* p) {
    f32x4 lo = *(const f32x4*)p;
    f32x4 hi = *(const f32x4*)(p + 4);
    bf16x8 r;
    #pragma unroll
    for (int j = 0; j < 4; ++j) { r[j] = (bf16)lo[j]; r[j + 4] = (bf16)hi[j]; }
    return r;
}

__global__ void transpose_f32_bf16(const float* __restrict__ in, bf16* __restrict__ out,
                                   int R, int C) {
    int idx = blockIdx.x * 256 + threadIdx.x;
    if (idx < R * C) {
        int r = idx / C, c = idx % C;
        out[(size_t)c * R + r] = (bf16)in[idx];
    }
}

__global__ void convert_f32_bf16(const float* __restrict__ in, bf16* __restrict__ out, int n) {
    int idx = blockIdx.x * 256 + threadIdx.x;
    if (idx < n) out[idx] = (bf16)in[idx];
}

// C[m][n] = sum_k A[m][k] * Bt[n][k].  64x64 block tile, 4 waves, each wave 32x32.
// AF32: A operand is float32, converted to bf16 in-register.
// transStore: C^T stored via LDS tile transpose (coalesced 128B rows).
template <int AF32>
__global__ void gemm_bt(const void* __restrict__ Av, const bf16* __restrict__ Bt,
                        bf16* __restrict__ C, int M, int N, int K,
                        long aStride, long cStride, int transStore, int ldct)
{
    __shared__ bf16 Tls[64][72];   // only used on transStore path; 144B rows (16B mult)

    int tid  = threadIdx.x;
    int lane = tid & 63;
    int wid  = tid >> 6;
    int l15  = lane & 15;
    int quad = lane >> 4;
    int nb = N >> 6;
    int gx = blockIdx.x % nb;
    int gy = blockIdx.x / nb;
    int m0 = gy * 64 + (wid & 1) * 32;
    int n0 = gx * 64 + (wid >> 1) * 32;

    f32x4 acc00 = 0, acc01 = 0, acc10 = 0, acc11 = 0;
    const bf16* br0 = Bt + (size_t)(n0 + l15) * K + quad * 8;
    const bf16* br1 = br0 + (size_t)16 * K;

    if (AF32) {
        const float* Ab  = (const float*)Av + (size_t)blockIdx.y * aStride;
        const float* ar0 = Ab + (size_t)(m0 + l15) * K + quad * 8;
        const float* ar1 = ar0 + (size_t)16 * K;
        for (int k0 = 0; k0 < K; k0 += 32) {
            bf16x8 a0 = ld_a_f32(ar0 + k0);
            bf16x8 a1 = ld_a_f32(ar1 + k0);
            bf16x8 b0 = *(const bf16x8*)(br0 + k0);
            bf16x8 b1 = *(const bf16x8*)(br1 + k0);
            acc00 = __builtin_amdgcn_mfma_f32_16x16x32_bf16(a0, b0, acc00, 0, 0, 0);
            acc01 = __builtin_amdgcn_mfma_f32_16x16x32_bf16(a0, b1, acc01, 0, 0, 0);
            acc10 = __builtin_amdgcn_mfma_f32_16x16x32_bf16(a1, b0, acc10, 0, 0, 0);
            acc11 = __builtin_amdgcn_mfma_f32_16x16x32_bf16(a1, b1, acc11, 0, 0, 0);
        }
    } else {
        const bf16* Ab  = (const bf16*)Av + (size_t)blockIdx.y * aStride;
        const bf16* ar0 = Ab + (size_t)(m0 + l15) * K + quad * 8;
        const bf16* ar1 = ar0 + (size_t)16 * K;
        for (int k0 = 0; k0 < K; k0 += 32) {
            bf16x8 a0 = *(const bf16x8*)(ar0 + k0);
            bf16x8 a1 = *(const bf16x8*)(ar1 + k0);
            bf16x8 b0 = *(const bf16x8*)(br0 + k0);
            bf16x8 b1 = *(const bf16x8*)(br1 + k0);
            acc00 = __builtin_amdgcn_mfma_f32_16x16x32_bf16(a0, b0, acc00, 0, 0, 0);
            acc01 = __builtin_amdgcn_mfma_f32_16x16x32_bf16(a0, b1, acc01, 0, 0, 0);
            acc10 = __builtin_amdgcn_mfma_f32_16x16x32_bf16(a1, b0, acc10, 0, 0, 0);
            acc11 = __builtin_amdgcn_mfma_f32_16x16x32_bf16(a1, b1, acc11, 0, 0, 0);
        }
    }

    bf16* Cb = C + (size_t)blockIdx.y * cStride;
    if (!transStore) {
        #pragma unroll
        for (int t = 0; t < 4; ++t) {
            f32x4 av = (t == 0) ? acc00 : (t == 1) ? acc01 : (t == 2) ? acc10 : acc11;
            int ti = t >> 1, tj = t & 1;
            #pragma unroll
            for (int r = 0; r < 4; ++r) {
                int m = m0 + ti * 16 + quad * 4 + r;
                int n = n0 + tj * 16 + l15;
                Cb[(size_t)m * N + n] = (bf16)av[r];
            }
        }
    } else {
        // stage C^T tile [n][m] in LDS, then coalesced row stores
        int mW = (wid & 1) * 32, nW = (wid >> 1) * 32;
        #pragma unroll
        for (int t = 0; t < 4; ++t) {
            f32x4 av = (t == 0) ? acc00 : (t == 1) ? acc01 : (t == 2) ? acc10 : acc11;
            int ti = t >> 1, tj = t & 1;
            int nL  = nW + tj * 16 + l15;
            int mL0 = mW + ti * 16 + quad * 4;
            bf16x4 pk;
            #pragma unroll
            for (int r = 0; r < 4; ++r) pk[r] = (bf16)av[r];
            *(bf16x4*)&Tls[nL][mL0] = pk;
        }
        __syncthreads();
        int r = tid >> 2, c = tid & 3;           // 64 rows x 4 chunks of 16 elems
        bf16x8 v0 = *(const bf16x8*)&Tls[r][c * 16];
        bf16x8 v1 = *(const bf16x8*)&Tls[r][c * 16 + 8];
        bf16* dst = Cb + (size_t)(gx * 64 + r) * ldct + gy * 64 + c * 16;
        *(bf16x8*)dst = v0;
        *(bf16x8*)(dst + 8) = v1;
    }
}

// Fused attention: per (batch, 32-row Q tile).  S=QK^T + skew(QE), online softmax, O=P·V.
// (256,1): grid is 256 blocks = 1 block/CU; do NOT let the compiler budget for 8
// waves/SIMD — at 64 VGPRs it spills the 64-reg accO to scratch (439 MB HBM writes, R2).
__launch_bounds__(256, 1)
__global__ void attn_kernel(const bf16* __restrict__ Qw, const bf16* __restrict__ Kw,
                            const bf16* __restrict__ Vt, const bf16* __restrict__ QE,
                            float* __restrict__ out)
{
    __shared__ bf16  Qs[BM][264];
    __shared__ float Ss[BM][68];
    __shared__ bf16  Ps[BM][72];
    __shared__ float mSt[BM], lSt[BM], aSt[BM];

    int tid  = threadIdx.x;
    int lane = tid & 63;
    int wid  = tid >> 6;
    int l15  = lane & 15;
    int quad = lane >> 4;

    int b  = blockIdx.x >> 6;
    int i0 = (blockIdx.x & 63) * BM;

    const bf16* Qb  = Qw + ((size_t)b * LL) * DKK;
    const bf16* Kb  = Kw + ((size_t)b * LL) * DKK;
    const bf16* QEb = QE + (size_t)b * LL * LL;

    {   // stage Q tile [32][256] into LDS
        int row = tid >> 3, sg = tid & 7;
        const bf16* src = Qb + (size_t)(i0 + row) * DKK + sg * 32;
        #pragma unroll
        for (int u = 0; u < 4; ++u)
            *(bf16x8*)&Qs[row][sg * 32 + u * 8] = *(const bf16x8*)(src + u * 8);
    }
    if (tid < BM) { mSt[tid] = -1e30f; lSt[tid] = 0.f; }
    __syncthreads();

    int ti  = wid & 1;
    int tjp = wid >> 1;
    int d0  = (wid >> 1) * 256;

    f32x4 accO[16];
    #pragma unroll
    for (int t = 0; t < 16; ++t) accO[t] = 0;

    for (int j0 = 0; j0 < LL; j0 += BN) {
        // ---- S = Q·K^T
        f32x4 s0 = 0, s1 = 0;
        const bf16* k0p = Kb + (size_t)(j0 + tjp * 32 + l15) * DKK + quad * 8;
        const bf16* k1p = k0p + (size_t)16 * DKK;
        #pragma unroll
        for (int ks = 0; ks < 8; ++ks) {
            bf16x8 a  = *(const bf16x8*)&Qs[ti * 16 + l15][ks * 32 + quad * 8];
            bf16x8 b0 = *(const bf16x8*)(k0p + ks * 32);
            bf16x8 b1 = *(const bf16x8*)(k1p + ks * 32);
            s0 = __builtin_amdgcn_mfma_f32_16x16x32_bf16(a, b0, s0, 0, 0, 0);
            s1 = __builtin_amdgcn_mfma_f32_16x16x32_bf16(a, b1, s1, 0, 0, 0);
        }
        // ---- add skewed relative logits: Srel[i][j] = j<=i ? QE[i][L-1-i+j]
        //      : (j==i+1 ? 0 : QE[i+1][j-i-2])
        #pragma unroll
        for (int t = 0; t < 2; ++t) {
            f32x4 s = t ? s1 : s0;
            int jc = j0 + tjp * 32 + t * 16 + l15;
            #pragma unroll
            for (int r = 0; r < 4; ++r) {
                int il = ti * 16 + quad * 4 + r;
                int i  = i0 + il;
                float srel = 0.f;
                if (jc <= i)         srel = (float)QEb[(size_t)i * LL + (LL - 1 - i + jc)];
                else if (jc > i + 1) srel = (float)QEb[(size_t)(i + 1) * LL + (jc - i - 2)];
                Ss[il][tjp * 32 + t * 16 + l15] = (s[r] + srel) * 0.0625f;
            }
        }
        __syncthreads();
        // ---- online softmax: 8 threads per row
        {
            int r = tid >> 3, sg = tid & 7;
            float v[8];
            #pragma unroll
            for (int c = 0; c < 8; ++c) v[c] = Ss[r][sg * 8 + c];
            float tmax = v[0];
            #pragma unroll
            for (int c = 1; c < 8; ++c) tmax = fmaxf(tmax, v[c]);
            tmax = fmaxf(tmax, __shfl_xor(tmax, 1));
            tmax = fmaxf(tmax, __shfl_xor(tmax, 2));
            tmax = fmaxf(tmax, __shfl_xor(tmax, 4));
            float mOld = mSt[r], lOld = lSt[r];
            float mNew = fmaxf(mOld, tmax);
            float alpha = __expf(mOld - mNew);
            float ps = 0.f;
            bf16x8 pv;
            #pragma unroll
            for (int c = 0; c < 8; ++c) {
                float p = __expf(v[c] - mNew);
                ps += p;
                pv[c] = (bf16)p;
            }
            ps += __shfl_xor(ps, 1);
            ps += __shfl_xor(ps, 2);
            ps += __shfl_xor(ps, 4);
            *(bf16x8*)&Ps[r][sg * 8] = pv;
            if (sg == 0) { mSt[r] = mNew; lSt[r] = alpha * lOld + ps; aSt[r] = alpha; }
        }
        __syncthreads();
        // ---- O = alpha*O + P·V
        bf16x8 aF0 = *(const bf16x8*)&Ps[ti * 16 + l15][quad * 8];
        bf16x8 aF1 = *(const bf16x8*)&Ps[ti * 16 + l15][32 + quad * 8];
        float ar[4];
        #pragma unroll
        for (int r = 0; r < 4; ++r) ar[r] = aSt[ti * 16 + quad * 4 + r];
        const bf16* vbase = Vt + (size_t)(d0 + l15) * (BB * LL) + (size_t)b * LL + j0 + quad * 8;
        #pragma unroll 4
        for (int td = 0; td < 16; ++td) {
            const bf16* vp = vbase + (size_t)td * 16 * (BB * LL);
            bf16x8 bF0 = *(const bf16x8*)(vp);
            bf16x8 bF1 = *(const bf16x8*)(vp + 32);
            f32x4 o = accO[td];
            o[0] *= ar[0]; o[1] *= ar[1]; o[2] *= ar[2]; o[3] *= ar[3];
            o = __builtin_amdgcn_mfma_f32_16x16x32_bf16(aF0, bF0, o, 0, 0, 0);
            o = __builtin_amdgcn_mfma_f32_16x16x32_bf16(aF1, bF1, o, 0, 0, 0);
            accO[td] = o;
        }
    }
    // ---- epilogue: divide by l, store f32
    float lr[4];
    #pragma unroll
    for (int r = 0; r < 4; ++r) lr[r] = 1.f / lSt[ti * 16 + quad * 4 + r];
    #pragma unroll 4
    for (int td = 0; td < 16; ++td) {
        #pragma unroll
        for (int r = 0; r < 4; ++r) {
            int i = i0 + ti * 16 + quad * 4 + r;
            int d = d0 + td * 16 + l15;
            out[((size_t)b * LL + i) * DD + d] = accO[td][r] * lr[r];
        }
    }
}

extern "C" void kernel_launch(void* const* d_in, const int* in_sizes, int n_in,
                              void* d_out, int out_size, void* d_ws, size_t ws_size,
                              hipStream_t stream) {
    const float* inQ = (const float*)d_in[0];
    const float* inK = (const float*)d_in[1];
    const float* inV = (const float*)d_in[2];
    const float* Wq  = (const float*)d_in[3];
    const float* Wk  = (const float*)d_in[4];
    const float* Wv  = (const float*)d_in[5];
    const float* E   = (const float*)d_in[6];
    float* out = (float*)d_out;

    char* ws = (char*)d_ws;
    bf16* Qw  = (bf16*)(ws);                         // 4 MB  [B,L,DK]
    bf16* Kw  = (bf16*)(ws + ((size_t)4  << 20));    // 4 MB  [B,L,DK]
    bf16* Vt  = (bf16*)(ws + ((size_t)8  << 20));    // 8 MB  [D, B*L]
    bf16* QEw = (bf16*)(ws + ((size_t)16 << 20));    // 32 MB [B,L,L]
    bf16* WqT = (bf16*)(ws + ((size_t)48 << 20));            // [DK,D]
    bf16* WkT = (bf16*)(ws + ((size_t)48 << 20) + 262144);   // [DK,D]
    bf16* WvT = (bf16*)(ws + ((size_t)48 << 20) + 524288);   // [D,D]
    bf16* Eb  = (bf16*)(ws + ((size_t)49 << 20));            // [L,DK] bf16

    transpose_f32_bf16<<<512,  256, 0, stream>>>(Wq, WqT, DD, DKK);
    transpose_f32_bf16<<<512,  256, 0, stream>>>(Wk, WkT, DD, DKK);
    transpose_f32_bf16<<<1024, 256, 0, stream>>>(Wv, WvT, DD, DD);
    convert_f32_bf16<<<2048, 256, 0, stream>>>(E, Eb, LL * DKK);

    // Q = inQ · Wq   (M=8192, N=256, K=512)
    gemm_bt<1><<<dim3(512, 1),  256, 0, stream>>>(inQ, WqT, Qw, BB*LL, DKK, DD, 0, 0, 0, 0);
    // K = inK · Wk
    gemm_bt<1><<<dim3(512, 1),  256, 0, stream>>>(inK, WkT, Kw, BB*LL, DKK, DD, 0, 0, 0, 0);
    // Vt = (inV · Wv)^T  stored [D][B*L]
    gemm_bt<1><<<dim3(1024, 1), 256, 0, stream>>>(inV, WvT, Vt, BB*LL, DD, DD, 0, 0, 1, BB*LL);
    // QE[b] = Q[b] · E^T  (M=N=2048, K=256), batched over blockIdx.y
    gemm_bt<0><<<dim3(1024, BB), 256, 0, stream>>>(Qw, Eb, QEw, LL, LL, DKK,
                                                   (long)LL*DKK, (long)LL*LL, 0, 0);
    // fused attention
    attn_kernel<<<dim3(BB * (LL / BM)), 256, 0, stream>>>(Qw, Kw, Vt, QEw, out);
}

// Round 4
// 503.512 us; speedup vs baseline: 1.1791x; 1.1718x over previous
//
#include <hip/hip_runtime.h>
#include <hip/hip_bf16.h>

#define BB 4
#define LL 2048
#define DD 512
#define DKK 256
#define BM 32
#define BN 64

typedef __bf16 bf16;
typedef __bf16 bf16x4 __attribute__((ext_vector_type(4)));
typedef __bf16 bf16x8 __attribute__((ext_vector_type(8)));
typedef float f32x4 __attribute__((ext_vector_type(4)));

__device__ inline bf16x8 ld_a_f32(const float* p) {
    f32x4 lo = *(const f32x4*)p;
    f32x4 hi = *(const f32x4*)(p + 4);
    bf16x8 r;
    #pragma unroll
    for (int j = 0; j < 4; ++j) { r[j] = (bf16)lo[j]; r[j + 4] = (bf16)hi[j]; }
    return r;
}

__global__ void transpose_f32_bf16(const float* __restrict__ in, bf16* __restrict__ out,
                                   int R, int C) {
    int idx = blockIdx.x * 256 + threadIdx.x;
    if (idx < R * C) {
        int r = idx / C, c = idx % C;
        out[(size_t)c * R + r] = (bf16)in[idx];
    }
}

__global__ void convert_f32_bf16(const float* __restrict__ in, bf16* __restrict__ out, int n) {
    int idx = blockIdx.x * 256 + threadIdx.x;
    if (idx < n) out[idx] = (bf16)in[idx];
}

// C[m][n] = sum_k A[m][k] * Bt[n][k].  64x64 block tile, 4 waves, each wave 32x32.
template <int AF32>
__global__ void gemm_bt(const void* __restrict__ Av, const bf16* __restrict__ Bt,
                        bf16* __restrict__ C, int M, int N, int K,
                        long aStride, long cStride, int transStore, int ldct)
{
    __shared__ bf16 Tls[64][72];

    int tid  = threadIdx.x;
    int lane = tid & 63;
    int wid  = tid >> 6;
    int l15  = lane & 15;
    int quad = lane >> 4;
    int nb = N >> 6;
    int gx = blockIdx.x % nb;
    int gy = blockIdx.x / nb;
    int m0 = gy * 64 + (wid & 1) * 32;
    int n0 = gx * 64 + (wid >> 1) * 32;

    f32x4 acc00 = 0, acc01 = 0, acc10 = 0, acc11 = 0;
    const bf16* br0 = Bt + (size_t)(n0 + l15) * K + quad * 8;
    const bf16* br1 = br0 + (size_t)16 * K;

    if (AF32) {
        const float* Ab  = (const float*)Av + (size_t)blockIdx.y * aStride;
        const float* ar0 = Ab + (size_t)(m0 + l15) * K + quad * 8;
        const float* ar1 = ar0 + (size_t)16 * K;
        for (int k0 = 0; k0 < K; k0 += 32) {
            bf16x8 a0 = ld_a_f32(ar0 + k0);
            bf16x8 a1 = ld_a_f32(ar1 + k0);
            bf16x8 b0 = *(const bf16x8*)(br0 + k0);
            bf16x8 b1 = *(const bf16x8*)(br1 + k0);
            acc00 = __builtin_amdgcn_mfma_f32_16x16x32_bf16(a0, b0, acc00, 0, 0, 0);
            acc01 = __builtin_amdgcn_mfma_f32_16x16x32_bf16(a0, b1, acc01, 0, 0, 0);
            acc10 = __builtin_amdgcn_mfma_f32_16x16x32_bf16(a1, b0, acc10, 0, 0, 0);
            acc11 = __builtin_amdgcn_mfma_f32_16x16x32_bf16(a1, b1, acc11, 0, 0, 0);
        }
    } else {
        const bf16* Ab  = (const bf16*)Av + (size_t)blockIdx.y * aStride;
        const bf16* ar0 = Ab + (size_t)(m0 + l15) * K + quad * 8;
        const bf16* ar1 = ar0 + (size_t)16 * K;
        for (int k0 = 0; k0 < K; k0 += 32) {
            bf16x8 a0 = *(const bf16x8*)(ar0 + k0);
            bf16x8 a1 = *(const bf16x8*)(ar1 + k0);
            bf16x8 b0 = *(const bf16x8*)(br0 + k0);
            bf16x8 b1 = *(const bf16x8*)(br1 + k0);
            acc00 = __builtin_amdgcn_mfma_f32_16x16x32_bf16(a0, b0, acc00, 0, 0, 0);
            acc01 = __builtin_amdgcn_mfma_f32_16x16x32_bf16(a0, b1, acc01, 0, 0, 0);
            acc10 = __builtin_amdgcn_mfma_f32_16x16x32_bf16(a1, b0, acc10, 0, 0, 0);
            acc11 = __builtin_amdgcn_mfma_f32_16x16x32_bf16(a1, b1, acc11, 0, 0, 0);
        }
    }

    bf16* Cb = C + (size_t)blockIdx.y * cStride;
    if (!transStore) {
        #pragma unroll
        for (int t = 0; t < 4; ++t) {
            f32x4 av = (t == 0) ? acc00 : (t == 1) ? acc01 : (t == 2) ? acc10 : acc11;
            int ti = t >> 1, tj = t & 1;
            #pragma unroll
            for (int r = 0; r < 4; ++r) {
                int m = m0 + ti * 16 + quad * 4 + r;
                int n = n0 + tj * 16 + l15;
                Cb[(size_t)m * N + n] = (bf16)av[r];
            }
        }
    } else {
        int mW = (wid & 1) * 32, nW = (wid >> 1) * 32;
        #pragma unroll
        for (int t = 0; t < 4; ++t) {
            f32x4 av = (t == 0) ? acc00 : (t == 1) ? acc01 : (t == 2) ? acc10 : acc11;
            int ti = t >> 1, tj = t & 1;
            int nL  = nW + tj * 16 + l15;
            int mL0 = mW + ti * 16 + quad * 4;
            bf16x4 pk;
            #pragma unroll
            for (int r = 0; r < 4; ++r) pk[r] = (bf16)av[r];
            *(bf16x4*)&Tls[nL][mL0] = pk;
        }
        __syncthreads();
        int r = tid >> 2, c = tid & 3;
        bf16x8 v0 = *(const bf16x8*)&Tls[r][c * 16];
        bf16x8 v1 = *(const bf16x8*)&Tls[r][c * 16 + 8];
        bf16* dst = Cb + (size_t)(gx * 64 + r) * ldct + gy * 64 + c * 16;
        *(bf16x8*)dst = v0;
        *(bf16x8*)(dst + 8) = v1;
    }
}

// Fused attention.  CRITICAL: all loops indexing accO[] must be FULLY unrolled —
// partial unroll leaves a dynamic index, forcing accO into scratch (R2/R3: 435 MB
// of HBM spill traffic, 6x slowdown).
__launch_bounds__(256, 1)
__global__ void attn_kernel(const bf16* __restrict__ Qw, const bf16* __restrict__ Kw,
                            const bf16* __restrict__ Vt, const bf16* __restrict__ QE,
                            float* __restrict__ out)
{
    __shared__ bf16  Qs[BM][264];
    __shared__ float Ss[BM][68];
    __shared__ bf16  Ps[BM][72];
    __shared__ float mSt[BM], lSt[BM], aSt[BM];

    int tid  = threadIdx.x;
    int lane = tid & 63;
    int wid  = tid >> 6;
    int l15  = lane & 15;
    int quad = lane >> 4;

    int b  = blockIdx.x >> 6;
    int i0 = (blockIdx.x & 63) * BM;

    const bf16* Qb  = Qw + ((size_t)b * LL) * DKK;
    const bf16* Kb  = Kw + ((size_t)b * LL) * DKK;
    const bf16* QEb = QE + (size_t)b * LL * LL;

    {
        int row = tid >> 3, sg = tid & 7;
        const bf16* src = Qb + (size_t)(i0 + row) * DKK + sg * 32;
        #pragma unroll
        for (int u = 0; u < 4; ++u)
            *(bf16x8*)&Qs[row][sg * 32 + u * 8] = *(const bf16x8*)(src + u * 8);
    }
    if (tid < BM) { mSt[tid] = -1e30f; lSt[tid] = 0.f; }
    __syncthreads();

    int ti  = wid & 1;
    int tjp = wid >> 1;
    int d0  = (wid >> 1) * 256;

    f32x4 accO[16];
    #pragma unroll
    for (int t = 0; t < 16; ++t) accO[t] = 0;

    for (int j0 = 0; j0 < LL; j0 += BN) {
        // ---- S = Q·K^T
        f32x4 s0 = 0, s1 = 0;
        const bf16* k0p = Kb + (size_t)(j0 + tjp * 32 + l15) * DKK + quad * 8;
        const bf16* k1p = k0p + (size_t)16 * DKK;
        #pragma unroll
        for (int ks = 0; ks < 8; ++ks) {
            bf16x8 a  = *(const bf16x8*)&Qs[ti * 16 + l15][ks * 32 + quad * 8];
            bf16x8 b0 = *(const bf16x8*)(k0p + ks * 32);
            bf16x8 b1 = *(const bf16x8*)(k1p + ks * 32);
            s0 = __builtin_amdgcn_mfma_f32_16x16x32_bf16(a, b0, s0, 0, 0, 0);
            s1 = __builtin_amdgcn_mfma_f32_16x16x32_bf16(a, b1, s1, 0, 0, 0);
        }
        // ---- Srel[i][j] = j<=i ? QE[i][L-1-i+j] : (j==i+1 ? 0 : QE[i+1][j-i-2])
        #pragma unroll
        for (int t = 0; t < 2; ++t) {
            f32x4 s = t ? s1 : s0;
            int jc = j0 + tjp * 32 + t * 16 + l15;
            #pragma unroll
            for (int r = 0; r < 4; ++r) {
                int il = ti * 16 + quad * 4 + r;
                int i  = i0 + il;
                float srel = 0.f;
                if (jc <= i)         srel = (float)QEb[(size_t)i * LL + (LL - 1 - i + jc)];
                else if (jc > i + 1) srel = (float)QEb[(size_t)(i + 1) * LL + (jc - i - 2)];
                Ss[il][tjp * 32 + t * 16 + l15] = (s[r] + srel) * 0.0625f;
            }
        }
        __syncthreads();
        // ---- online softmax
        {
            int r = tid >> 3, sg = tid & 7;
            float v[8];
            #pragma unroll
            for (int c = 0; c < 8; ++c) v[c] = Ss[r][sg * 8 + c];
            float tmax = v[0];
            #pragma unroll
            for (int c = 1; c < 8; ++c) tmax = fmaxf(tmax, v[c]);
            tmax = fmaxf(tmax, __shfl_xor(tmax, 1));
            tmax = fmaxf(tmax, __shfl_xor(tmax, 2));
            tmax = fmaxf(tmax, __shfl_xor(tmax, 4));
            float mOld = mSt[r], lOld = lSt[r];
            float mNew = fmaxf(mOld, tmax);
            float alpha = __expf(mOld - mNew);
            float ps = 0.f;
            bf16x8 pv;
            #pragma unroll
            for (int c = 0; c < 8; ++c) {
                float p = __expf(v[c] - mNew);
                ps += p;
                pv[c] = (bf16)p;
            }
            ps += __shfl_xor(ps, 1);
            ps += __shfl_xor(ps, 2);
            ps += __shfl_xor(ps, 4);
            *(bf16x8*)&Ps[r][sg * 8] = pv;
            if (sg == 0) { mSt[r] = mNew; lSt[r] = alpha * lOld + ps; aSt[r] = alpha; }
        }
        __syncthreads();
        // ---- O = alpha*O + P·V   (FULL unroll — accO must stay in registers)
        bf16x8 aF0 = *(const bf16x8*)&Ps[ti * 16 + l15][quad * 8];
        bf16x8 aF1 = *(const bf16x8*)&Ps[ti * 16 + l15][32 + quad * 8];
        float ar[4];
        #pragma unroll
        for (int r = 0; r < 4; ++r) ar[r] = aSt[ti * 16 + quad * 4 + r];
        const bf16* vbase = Vt + (size_t)(d0 + l15) * (BB * LL) + (size_t)b * LL + j0 + quad * 8;
        #pragma unroll
        for (int td = 0; td < 16; ++td) {
            const bf16* vp = vbase + (size_t)td * 16 * (BB * LL);
            bf16x8 bF0 = *(const bf16x8*)(vp);
            bf16x8 bF1 = *(const bf16x8*)(vp + 32);
            f32x4 o = accO[td];
            o[0] *= ar[0]; o[1] *= ar[1]; o[2] *= ar[2]; o[3] *= ar[3];
            o = __builtin_amdgcn_mfma_f32_16x16x32_bf16(aF0, bF0, o, 0, 0, 0);
            o = __builtin_amdgcn_mfma_f32_16x16x32_bf16(aF1, bF1, o, 0, 0, 0);
            accO[td] = o;
        }
    }
    // ---- epilogue (FULL unroll)
    float lr[4];
    #pragma unroll
    for (int r = 0; r < 4; ++r) lr[r] = 1.f / lSt[ti * 16 + quad * 4 + r];
    #pragma unroll
    for (int td = 0; td < 16; ++td) {
        #pragma unroll
        for (int r = 0; r < 4; ++r) {
            int i = i0 + ti * 16 + quad * 4 + r;
            int d = d0 + td * 16 + l15;
            out[((size_t)b * LL + i) * DD + d] = accO[td][r] * lr[r];
        }
    }
}

extern "C" void kernel_launch(void* const* d_in, const int* in_sizes, int n_in,
                              void* d_out, int out_size, void* d_ws, size_t ws_size,
                              hipStream_t stream) {
    const float* inQ = (const float*)d_in[0];
    const float* inK = (const float*)d_in[1];
    const float* inV = (const float*)d_in[2];
    const float* Wq  = (const float*)d_in[3];
    const float* Wk  = (const float*)d_in[4];
    const float* Wv  = (const float*)d_in[5];
    const float* E   = (const float*)d_in[6];
    float* out = (float*)d_out;

    char* ws = (char*)d_ws;
    bf16* Qw  = (bf16*)(ws);                         // 4 MB  [B,L,DK]
    bf16* Kw  = (bf16*)(ws + ((size_t)4  << 20));    // 4 MB  [B,L,DK]
    bf16* Vt  = (bf16*)(ws + ((size_t)8  << 20));    // 8 MB  [D, B*L]
    bf16* QEw = (bf16*)(ws + ((size_t)16 << 20));    // 32 MB [B,L,L]
    bf16* WqT = (bf16*)(ws + ((size_t)48 << 20));
    bf16* WkT = (bf16*)(ws + ((size_t)48 << 20) + 262144);
    bf16* WvT = (bf16*)(ws + ((size_t)48 << 20) + 524288);
    bf16* Eb  = (bf16*)(ws + ((size_t)49 << 20));

    transpose_f32_bf16<<<512,  256, 0, stream>>>(Wq, WqT, DD, DKK);
    transpose_f32_bf16<<<512,  256, 0, stream>>>(Wk, WkT, DD, DKK);
    transpose_f32_bf16<<<1024, 256, 0, stream>>>(Wv, WvT, DD, DD);
    convert_f32_bf16<<<2048, 256, 0, stream>>>(E, Eb, LL * DKK);

    gemm_bt<1><<<dim3(512, 1),  256, 0, stream>>>(inQ, WqT, Qw, BB*LL, DKK, DD, 0, 0, 0, 0);
    gemm_bt<1><<<dim3(512, 1),  256, 0, stream>>>(inK, WkT, Kw, BB*LL, DKK, DD, 0, 0, 0, 0);
    gemm_bt<1><<<dim3(1024, 1), 256, 0, stream>>>(inV, WvT, Vt, BB*LL, DD, DD, 0, 0, 1, BB*LL);
    gemm_bt<0><<<dim3(1024, BB), 256, 0, stream>>>(Qw, Eb, QEw, LL, LL, DKK,
                                                   (long)LL*DKK, (long)LL*LL, 0, 0);
    attn_kernel<<<dim3(BB * (LL / BM)), 256, 0, stream>>>(Qw, Kw, Vt, QEw, out);
}

// Round 5
// 418.263 us; speedup vs baseline: 1.4194x; 1.2038x over previous
//
#include <hip/hip_runtime.h>
#include <hip/hip_bf16.h>

#define BB 4
#define LL 2048
#define DD 512
#define DKK 256
#define BM 32
#define BN 64

typedef __bf16 bf16;
typedef __bf16 bf16x4 __attribute__((ext_vector_type(4)));
typedef __bf16 bf16x8 __attribute__((ext_vector_type(8)));
typedef float f32x4 __attribute__((ext_vector_type(4)));

__device__ inline bf16x8 ld_a_f32(const float* p) {
    f32x4 lo = *(const f32x4*)p;
    f32x4 hi = *(const f32x4*)(p + 4);
    bf16x8 r;
    #pragma unroll
    for (int j = 0; j < 4; ++j) { r[j] = (bf16)lo[j]; r[j + 4] = (bf16)hi[j]; }
    return r;
}

__global__ void transpose_f32_bf16(const float* __restrict__ in, bf16* __restrict__ out,
                                   int R, int C) {
    int idx = blockIdx.x * 256 + threadIdx.x;
    if (idx < R * C) {
        int r = idx / C, c = idx % C;
        out[(size_t)c * R + r] = (bf16)in[idx];
    }
}

// C[m][n] = sum_k A[m][k] * Bt[n][k].  64x64 block tile, 4 waves, each wave 32x32.
// SKEW: scatter-store into the skewed Srel layout:
//   QE[r][c] -> (c >= L-1-r) ? Srel[r][c-(L-1-r)] : (r>=1 ? Srel[r-1][c+r+1] : drop)
//   (Srel[i][i+1] is never written; attn masks it.)
template <int AF32, int SKEW>
__global__ void gemm_bt(const void* __restrict__ Av, const bf16* __restrict__ Bt,
                        bf16* __restrict__ C, int M, int N, int K,
                        long aStride, long cStride, int transStore, int ldct)
{
    __shared__ bf16 Tls[64][72];

    int tid  = threadIdx.x;
    int lane = tid & 63;
    int wid  = tid >> 6;
    int l15  = lane & 15;
    int quad = lane >> 4;
    int nb = N >> 6;
    int gx = blockIdx.x % nb;
    int gy = blockIdx.x / nb;
    int m0 = gy * 64 + (wid & 1) * 32;
    int n0 = gx * 64 + (wid >> 1) * 32;

    f32x4 acc00 = 0, acc01 = 0, acc10 = 0, acc11 = 0;
    const bf16* br0 = Bt + (size_t)(n0 + l15) * K + quad * 8;
    const bf16* br1 = br0 + (size_t)16 * K;

    if (AF32) {
        const float* Ab  = (const float*)Av + (size_t)blockIdx.y * aStride;
        const float* ar0 = Ab + (size_t)(m0 + l15) * K + quad * 8;
        const float* ar1 = ar0 + (size_t)16 * K;
        for (int k0 = 0; k0 < K; k0 += 32) {
            bf16x8 a0 = ld_a_f32(ar0 + k0);
            bf16x8 a1 = ld_a_f32(ar1 + k0);
            bf16x8 b0 = *(const bf16x8*)(br0 + k0);
            bf16x8 b1 = *(const bf16x8*)(br1 + k0);
            acc00 = __builtin_amdgcn_mfma_f32_16x16x32_bf16(a0, b0, acc00, 0, 0, 0);
            acc01 = __builtin_amdgcn_mfma_f32_16x16x32_bf16(a0, b1, acc01, 0, 0, 0);
            acc10 = __builtin_amdgcn_mfma_f32_16x16x32_bf16(a1, b0, acc10, 0, 0, 0);
            acc11 = __builtin_amdgcn_mfma_f32_16x16x32_bf16(a1, b1, acc11, 0, 0, 0);
        }
    } else {
        const bf16* Ab  = (const bf16*)Av + (size_t)blockIdx.y * aStride;
        const bf16* ar0 = Ab + (size_t)(m0 + l15) * K + quad * 8;
        const bf16* ar1 = ar0 + (size_t)16 * K;
        for (int k0 = 0; k0 < K; k0 += 32) {
            bf16x8 a0 = *(const bf16x8*)(ar0 + k0);
            bf16x8 a1 = *(const bf16x8*)(ar1 + k0);
            bf16x8 b0 = *(const bf16x8*)(br0 + k0);
            bf16x8 b1 = *(const bf16x8*)(br1 + k0);
            acc00 = __builtin_amdgcn_mfma_f32_16x16x32_bf16(a0, b0, acc00, 0, 0, 0);
            acc01 = __builtin_amdgcn_mfma_f32_16x16x32_bf16(a0, b1, acc01, 0, 0, 0);
            acc10 = __builtin_amdgcn_mfma_f32_16x16x32_bf16(a1, b0, acc10, 0, 0, 0);
            acc11 = __builtin_amdgcn_mfma_f32_16x16x32_bf16(a1, b1, acc11, 0, 0, 0);
        }
    }

    bf16* Cb = C + (size_t)blockIdx.y * cStride;
    if (SKEW) {
        #pragma unroll
        for (int t = 0; t < 4; ++t) {
            f32x4 av = (t == 0) ? acc00 : (t == 1) ? acc01 : (t == 2) ? acc10 : acc11;
            int ti = t >> 1, tj = t & 1;
            #pragma unroll
            for (int r = 0; r < 4; ++r) {
                int row = m0 + ti * 16 + quad * 4 + r;
                int c   = n0 + tj * 16 + l15;
                bool lower = (c >= LL - 1 - row);
                int dr = lower ? row : row - 1;
                int dc = lower ? c - (LL - 1 - row) : c + row + 1;
                if (lower || row >= 1)
                    Cb[(size_t)dr * LL + dc] = (bf16)av[r];
            }
        }
    } else if (!transStore) {
        #pragma unroll
        for (int t = 0; t < 4; ++t) {
            f32x4 av = (t == 0) ? acc00 : (t == 1) ? acc01 : (t == 2) ? acc10 : acc11;
            int ti = t >> 1, tj = t & 1;
            #pragma unroll
            for (int r = 0; r < 4; ++r) {
                int m = m0 + ti * 16 + quad * 4 + r;
                int n = n0 + tj * 16 + l15;
                Cb[(size_t)m * N + n] = (bf16)av[r];
            }
        }
    } else {
        int mW = (wid & 1) * 32, nW = (wid >> 1) * 32;
        #pragma unroll
        for (int t = 0; t < 4; ++t) {
            f32x4 av = (t == 0) ? acc00 : (t == 1) ? acc01 : (t == 2) ? acc10 : acc11;
            int ti = t >> 1, tj = t & 1;
            int nL  = nW + tj * 16 + l15;
            int mL0 = mW + ti * 16 + quad * 4;
            bf16x4 pk;
            #pragma unroll
            for (int r = 0; r < 4; ++r) pk[r] = (bf16)av[r];
            *(bf16x4*)&Tls[nL][mL0] = pk;
        }
        __syncthreads();
        int r = tid >> 2, c = tid & 3;
        bf16x8 v0 = *(const bf16x8*)&Tls[r][c * 16];
        bf16x8 v1 = *(const bf16x8*)&Tls[r][c * 16 + 8];
        bf16* dst = Cb + (size_t)(gx * 64 + r) * ldct + gy * 64 + c * 16;
        *(bf16x8*)dst = v0;
        *(bf16x8*)(dst + 8) = v1;
    }
}

// Fused attention.  Q in registers; K-tile staged in LDS (coalesced); Srel read
// coalesced from the pre-skewed tensor; each wave owns a d-quarter for PV (1x V
// traffic).  All accO-indexing loops fully unrolled (R3: dynamic index => scratch).
__launch_bounds__(256, 1)
__global__ void attn_kernel(const bf16* __restrict__ Qw, const bf16* __restrict__ Kw,
                            const bf16* __restrict__ Vt, const bf16* __restrict__ Srel,
                            float* __restrict__ out)
{
    __shared__ bf16  Klds[BN][DKK + 8];   // [64][264] pitch 528B -> 2-way reads (free)
    __shared__ float Ss[BM][68];
    __shared__ bf16  Ps[BM][72];
    __shared__ float mSt[BM], lSt[BM], aSt[BM];

    int tid  = threadIdx.x;
    int lane = tid & 63;
    int wid  = tid >> 6;
    int l15  = lane & 15;
    int quad = lane >> 4;

    int b  = blockIdx.x >> 6;
    int i0 = (blockIdx.x & 63) * BM;

    const bf16* Qb  = Qw + ((size_t)b * LL) * DKK;
    const bf16* Kb  = Kw + ((size_t)b * LL) * DKK;
    const bf16* Sb  = Srel + (size_t)b * LL * LL;

    // Q fragments in registers: rows i0 + rt*16 + l15, all 256 k (one-time gather)
    bf16x8 Qreg[2][8];
    #pragma unroll
    for (int rt = 0; rt < 2; ++rt)
        #pragma unroll
        for (int ks = 0; ks < 8; ++ks)
            Qreg[rt][ks] = *(const bf16x8*)(Qb + (size_t)(i0 + rt * 16 + l15) * DKK
                                            + ks * 32 + quad * 8);

    if (tid < BM) { mSt[tid] = -1e30f; lSt[tid] = 0.f; }

    int d0 = wid * 128;   // PV d-quarter per wave
    f32x4 accO[2][8];
    #pragma unroll
    for (int rt = 0; rt < 2; ++rt)
        #pragma unroll
        for (int nt = 0; nt < 8; ++nt) accO[rt][nt] = 0;

    for (int j0 = 0; j0 < LL; j0 += BN) {
        // ---- stage K tile [64][256] into LDS, fully coalesced
        #pragma unroll
        for (int u = 0; u < 8; ++u) {
            int id = u * 256 + tid;
            int jr = id >> 5, ck = id & 31;
            *(bf16x8*)&Klds[jr][ck * 8] =
                *(const bf16x8*)(Kb + (size_t)(j0 + jr) * DKK + ck * 8);
        }
        __syncthreads();
        // ---- S = Q·K^T : wave w owns 16-col strip, both 16-row tiles
        f32x4 s0 = 0, s1 = 0;
        #pragma unroll
        for (int ks = 0; ks < 8; ++ks) {
            bf16x8 kf = *(const bf16x8*)&Klds[wid * 16 + l15][ks * 32 + quad * 8];
            s0 = __builtin_amdgcn_mfma_f32_16x16x32_bf16(Qreg[0][ks], kf, s0, 0, 0, 0);
            s1 = __builtin_amdgcn_mfma_f32_16x16x32_bf16(Qreg[1][ks], kf, s1, 0, 0, 0);
        }
        #pragma unroll
        for (int r = 0; r < 4; ++r) {
            Ss[quad * 4 + r][wid * 16 + l15]      = s0[r];
            Ss[16 + quad * 4 + r][wid * 16 + l15] = s1[r];
        }
        __syncthreads();
        // ---- online softmax: 8 threads per row; Srel added here (coalesced load)
        {
            int r = tid >> 3, sg = tid & 7;
            int i = i0 + r;
            bf16x8 s8 = *(const bf16x8*)(Sb + (size_t)i * LL + j0 + sg * 8);
            float v[8];
            #pragma unroll
            for (int c = 0; c < 8; ++c) {
                float sr = (j0 + sg * 8 + c == i + 1) ? 0.f : (float)s8[c];
                v[c] = (Ss[r][sg * 8 + c] + sr) * 0.0625f;
            }
            float tmax = v[0];
            #pragma unroll
            for (int c = 1; c < 8; ++c) tmax = fmaxf(tmax, v[c]);
            tmax = fmaxf(tmax, __shfl_xor(tmax, 1));
            tmax = fmaxf(tmax, __shfl_xor(tmax, 2));
            tmax = fmaxf(tmax, __shfl_xor(tmax, 4));
            float mOld = mSt[r], lOld = lSt[r];
            float mNew = fmaxf(mOld, tmax);
            float alpha = __expf(mOld - mNew);
            float ps = 0.f;
            bf16x8 pv;
            #pragma unroll
            for (int c = 0; c < 8; ++c) {
                float p = __expf(v[c] - mNew);
                ps += p;
                pv[c] = (bf16)p;
            }
            ps += __shfl_xor(ps, 1);
            ps += __shfl_xor(ps, 2);
            ps += __shfl_xor(ps, 4);
            *(bf16x8*)&Ps[r][sg * 8] = pv;
            if (sg == 0) { mSt[r] = mNew; lSt[r] = alpha * lOld + ps; aSt[r] = alpha; }
        }
        __syncthreads();
        // ---- O = alpha*O + P·V : wave owns d-quarter [128 cols], both row tiles
        bf16x8 aF[2][2];
        #pragma unroll
        for (int rt = 0; rt < 2; ++rt)
            #pragma unroll
            for (int kk = 0; kk < 2; ++kk)
                aF[rt][kk] = *(const bf16x8*)&Ps[rt * 16 + l15][kk * 32 + quad * 8];
        float ar[2][4];
        #pragma unroll
        for (int rt = 0; rt < 2; ++rt)
            #pragma unroll
            for (int r = 0; r < 4; ++r) ar[rt][r] = aSt[rt * 16 + quad * 4 + r];
        const bf16* vbase = Vt + (size_t)(d0 + l15) * (BB * LL) + (size_t)b * LL + j0 + quad * 8;
        #pragma unroll
        for (int nt = 0; nt < 8; ++nt) {
            const bf16* vp = vbase + (size_t)nt * 16 * (BB * LL);
            bf16x8 bF0 = *(const bf16x8*)(vp);
            bf16x8 bF1 = *(const bf16x8*)(vp + 32);
            #pragma unroll
            for (int rt = 0; rt < 2; ++rt) {
                f32x4 o = accO[rt][nt];
                o[0] *= ar[rt][0]; o[1] *= ar[rt][1]; o[2] *= ar[rt][2]; o[3] *= ar[rt][3];
                o = __builtin_amdgcn_mfma_f32_16x16x32_bf16(aF[rt][0], bF0, o, 0, 0, 0);
                o = __builtin_amdgcn_mfma_f32_16x16x32_bf16(aF[rt][1], bF1, o, 0, 0, 0);
                accO[rt][nt] = o;
            }
        }
        __syncthreads();   // protect Klds before next-iter staging
    }
    // ---- epilogue
    float lr[2][4];
    #pragma unroll
    for (int rt = 0; rt < 2; ++rt)
        #pragma unroll
        for (int r = 0; r < 4; ++r) lr[rt][r] = 1.f / lSt[rt * 16 + quad * 4 + r];
    #pragma unroll
    for (int rt = 0; rt < 2; ++rt)
        #pragma unroll
        for (int nt = 0; nt < 8; ++nt)
            #pragma unroll
            for (int r = 0; r < 4; ++r) {
                int i = i0 + rt * 16 + quad * 4 + r;
                int d = d0 + nt * 16 + l15;
                out[((size_t)b * LL + i) * DD + d] = accO[rt][nt][r] * lr[rt][r];
            }
}

extern "C" void kernel_launch(void* const* d_in, const int* in_sizes, int n_in,
                              void* d_out, int out_size, void* d_ws, size_t ws_size,
                              hipStream_t stream) {
    const float* inQ = (const float*)d_in[0];
    const float* inK = (const float*)d_in[1];
    const float* inV = (const float*)d_in[2];
    const float* Wq  = (const float*)d_in[3];
    const float* Wk  = (const float*)d_in[4];
    const float* Wv  = (const float*)d_in[5];
    const float* E   = (const float*)d_in[6];
    float* out = (float*)d_out;

    char* ws = (char*)d_ws;
    bf16* Qw   = (bf16*)(ws);                         // 4 MB  [B,L,DK]
    bf16* Kw   = (bf16*)(ws + ((size_t)4  << 20));    // 4 MB  [B,L,DK]
    bf16* Vt   = (bf16*)(ws + ((size_t)8  << 20));    // 8 MB  [D, B*L]
    bf16* SrelW= (bf16*)(ws + ((size_t)16 << 20));    // 32 MB [B,L,L] (skewed)
    bf16* WqT  = (bf16*)(ws + ((size_t)48 << 20));
    bf16* WkT  = (bf16*)(ws + ((size_t)48 << 20) + 262144);
    bf16* WvT  = (bf16*)(ws + ((size_t)48 << 20) + 524288);
    bf16* EbT  = (bf16*)(ws + ((size_t)49 << 20));    // E as [L][DK] bf16 (row copy)

    transpose_f32_bf16<<<512,  256, 0, stream>>>(Wq, WqT, DD, DKK);
    transpose_f32_bf16<<<512,  256, 0, stream>>>(Wk, WkT, DD, DKK);
    transpose_f32_bf16<<<1024, 256, 0, stream>>>(Wv, WvT, DD, DD);
    // E needs no transpose for gemm_bt (Bt = E rows over k) — just f32->bf16 copy:
    {
        int n = LL * DKK;
        transpose_f32_bf16<<<(n + 255) / 256, 256, 0, stream>>>(E, EbT, 1, n); // R=1 => identity
    }

    gemm_bt<1,0><<<dim3(512, 1),  256, 0, stream>>>(inQ, WqT, Qw, BB*LL, DKK, DD, 0, 0, 0, 0);
    gemm_bt<1,0><<<dim3(512, 1),  256, 0, stream>>>(inK, WkT, Kw, BB*LL, DKK, DD, 0, 0, 0, 0);
    gemm_bt<1,0><<<dim3(1024, 1), 256, 0, stream>>>(inV, WvT, Vt, BB*LL, DD, DD, 0, 0, 1, BB*LL);
    // QE -> skewed Srel directly
    gemm_bt<0,1><<<dim3(1024, BB), 256, 0, stream>>>(Qw, EbT, SrelW, LL, LL, DKK,
                                                     (long)LL*DKK, (long)LL*LL, 0, 0);
    attn_kernel<<<dim3(BB * (LL / BM)), 256, 0, stream>>>(Qw, Kw, Vt, SrelW, out);
}

// Round 6
// 374.460 us; speedup vs baseline: 1.5854x; 1.1170x over previous
//
#include <hip/hip_runtime.h>
#include <hip/hip_bf16.h>

#define BB 4
#define LL 2048
#define DD 512
#define DKK 256

typedef __bf16 bf16;
typedef __bf16 bf16x4 __attribute__((ext_vector_type(4)));
typedef __bf16 bf16x8 __attribute__((ext_vector_type(8)));
typedef float f32x4 __attribute__((ext_vector_type(4)));

__global__ void transpose_f32_bf16(const float* __restrict__ in, bf16* __restrict__ out,
                                   int R, int C) {
    int idx = blockIdx.x * 256 + threadIdx.x;
    if (idx < R * C) {
        int r = idx / C, c = idx % C;
        out[(size_t)c * R + r] = (bf16)in[idx];
    }
}

// C[m][n] = sum_k A[m][k] * Bt[n][k].  64x64 tile, 4 waves (each 32x32).
// A staged via double-buffered LDS (coalesced rows, f32->bf16 in-flight);
// B (small weight matrices, L2-resident) read direct.
// SKEW: scatter-store into skewed Srel layout:
//   QE[r][c] -> (c >= L-1-r) ? Srel[r][c-(L-1-r)] : (r>=1 ? Srel[r-1][c+r+1] : drop)
template <int AF32, int SKEW>
__global__ void gemm_bt(const void* __restrict__ Av, const bf16* __restrict__ Bt,
                        bf16* __restrict__ C, int M, int N, int K,
                        long aStride, long cStride, int transStore, int ldct)
{
    __shared__ bf16 Als[2][64][40];   // pitch 80B (16B mult); 2-way frag reads (free)
    __shared__ bf16 Tls[64][72];      // transStore epilogue only

    int tid  = threadIdx.x;
    int lane = tid & 63;
    int wid  = tid >> 6;
    int l15  = lane & 15;
    int quad = lane >> 4;
    int nb = N >> 6;
    int gx = blockIdx.x % nb;
    int gy = blockIdx.x / nb;
    int m0 = gy * 64 + (wid & 1) * 32;
    int n0 = gx * 64 + (wid >> 1) * 32;

    int rowA = tid >> 2;            // 0..63
    int offA = (tid & 3) * 8;       // k-offset within 32-chunk

    const float* aPtrF = nullptr;
    const bf16*  aPtrB = nullptr;
    if (AF32) aPtrF = (const float*)Av + (size_t)blockIdx.y * aStride
                      + (size_t)(gy * 64 + rowA) * K + offA;
    else      aPtrB = (const bf16*)Av + (size_t)blockIdx.y * aStride
                      + (size_t)(gy * 64 + rowA) * K + offA;

    const bf16* br0 = Bt + (size_t)(n0 + l15) * K + quad * 8;
    const bf16* br1 = br0 + (size_t)16 * K;

    f32x4 acc00 = 0, acc01 = 0, acc10 = 0, acc11 = 0;

    // stage step 0
    if (AF32) {
        f32x4 lo = *(const f32x4*)(aPtrF);
        f32x4 hi = *(const f32x4*)(aPtrF + 4);
        bf16x8 pk;
        #pragma unroll
        for (int j = 0; j < 4; ++j) { pk[j] = (bf16)lo[j]; pk[j + 4] = (bf16)hi[j]; }
        *(bf16x8*)&Als[0][rowA][offA] = pk;
    } else {
        *(bf16x8*)&Als[0][rowA][offA] = *(const bf16x8*)(aPtrB);
    }

    int nsteps = K >> 5;
    for (int s = 0; s < nsteps; ++s) {
        __syncthreads();
        if (s + 1 < nsteps) {
            if (AF32) {
                f32x4 lo = *(const f32x4*)(aPtrF + (s + 1) * 32);
                f32x4 hi = *(const f32x4*)(aPtrF + (s + 1) * 32 + 4);
                bf16x8 pk;
                #pragma unroll
                for (int j = 0; j < 4; ++j) { pk[j] = (bf16)lo[j]; pk[j + 4] = (bf16)hi[j]; }
                *(bf16x8*)&Als[(s + 1) & 1][rowA][offA] = pk;
            } else {
                *(bf16x8*)&Als[(s + 1) & 1][rowA][offA] =
                    *(const bf16x8*)(aPtrB + (s + 1) * 32);
            }
        }
        bf16x8 a0 = *(const bf16x8*)&Als[s & 1][(wid & 1) * 32 + l15][quad * 8];
        bf16x8 a1 = *(const bf16x8*)&Als[s & 1][(wid & 1) * 32 + 16 + l15][quad * 8];
        bf16x8 b0 = *(const bf16x8*)(br0 + s * 32);
        bf16x8 b1 = *(const bf16x8*)(br1 + s * 32);
        acc00 = __builtin_amdgcn_mfma_f32_16x16x32_bf16(a0, b0, acc00, 0, 0, 0);
        acc01 = __builtin_amdgcn_mfma_f32_16x16x32_bf16(a0, b1, acc01, 0, 0, 0);
        acc10 = __builtin_amdgcn_mfma_f32_16x16x32_bf16(a1, b0, acc10, 0, 0, 0);
        acc11 = __builtin_amdgcn_mfma_f32_16x16x32_bf16(a1, b1, acc11, 0, 0, 0);
    }

    bf16* Cb = C + (size_t)blockIdx.y * cStride;
    if (SKEW) {
        #pragma unroll
        for (int t = 0; t < 4; ++t) {
            f32x4 av = (t == 0) ? acc00 : (t == 1) ? acc01 : (t == 2) ? acc10 : acc11;
            int ti = t >> 1, tj = t & 1;
            #pragma unroll
            for (int r = 0; r < 4; ++r) {
                int row = m0 + ti * 16 + quad * 4 + r;
                int c   = n0 + tj * 16 + l15;
                bool lower = (c >= LL - 1 - row);
                int dr = lower ? row : row - 1;
                int dc = lower ? c - (LL - 1 - row) : c + row + 1;
                if (lower || row >= 1)
                    Cb[(size_t)dr * LL + dc] = (bf16)av[r];
            }
        }
    } else if (!transStore) {
        #pragma unroll
        for (int t = 0; t < 4; ++t) {
            f32x4 av = (t == 0) ? acc00 : (t == 1) ? acc01 : (t == 2) ? acc10 : acc11;
            int ti = t >> 1, tj = t & 1;
            #pragma unroll
            for (int r = 0; r < 4; ++r) {
                int m = m0 + ti * 16 + quad * 4 + r;
                int n = n0 + tj * 16 + l15;
                Cb[(size_t)m * N + n] = (bf16)av[r];
            }
        }
    } else {
        int mW = (wid & 1) * 32, nW = (wid >> 1) * 32;
        __syncthreads();
        #pragma unroll
        for (int t = 0; t < 4; ++t) {
            f32x4 av = (t == 0) ? acc00 : (t == 1) ? acc01 : (t == 2) ? acc10 : acc11;
            int ti = t >> 1, tj = t & 1;
            int nL  = nW + tj * 16 + l15;
            int mL0 = mW + ti * 16 + quad * 4;
            bf16x4 pk;
            #pragma unroll
            for (int r = 0; r < 4; ++r) pk[r] = (bf16)av[r];
            *(bf16x4*)&Tls[nL][mL0] = pk;
        }
        __syncthreads();
        int r = tid >> 2, c = tid & 3;
        bf16x8 v0 = *(const bf16x8*)&Tls[r][c * 16];
        bf16x8 v1 = *(const bf16x8*)&Tls[r][c * 16 + 8];
        bf16* dst = Cb + (size_t)(gx * 64 + r) * ldct + gy * 64 + c * 16;
        *(bf16x8*)dst = v0;
        *(bf16x8*)(dst + 8) = v1;
    }
}

// Fused attention, occupancy-tiled: BM=16 Q-rows, each block owns a 256-col
// d-half (S work duplicated 2x — cheap), grid = 4*128*2 = 1024 blocks = 4/CU.
// LDS 40.5 KB => 4 blocks/CU resident; __launch_bounds__(256,4) caps VGPR at 128.
// All accO loops fully unrolled (R3: dynamic index => scratch spill).
__launch_bounds__(256, 4)
__global__ void attn_kernel(const bf16* __restrict__ Qw, const bf16* __restrict__ Kw,
                            const bf16* __restrict__ Vt, const bf16* __restrict__ Srel,
                            float* __restrict__ out)
{
    __shared__ bf16  Klds[64][264];   // pitch 528B: 16B-mult, 2-way frag reads (free)
    __shared__ float Ss[16][66];
    __shared__ bf16  Ps[16][72];      // pitch 144B: 16B-mult for ds_read_b128
    __shared__ float mSt[16], lSt[16], aSt[16];

    int tid  = threadIdx.x;
    int lane = tid & 63;
    int wid  = tid >> 6;
    int l15  = lane & 15;
    int quad = lane >> 4;

    int dh = blockIdx.x & 1;           // d-half
    int it = blockIdx.x >> 1;
    int i0 = (it & 127) * 16;
    int b  = it >> 7;

    const bf16* Qb = Qw + (size_t)b * LL * DKK;
    const bf16* Kb = Kw + (size_t)b * LL * DKK;
    const bf16* Sb = Srel + (size_t)b * LL * LL;

    // Q fragments in registers (one-time gather): rows i0+l15, k = ks*32+quad*8
    bf16x8 Qreg[8];
    #pragma unroll
    for (int ks = 0; ks < 8; ++ks)
        Qreg[ks] = *(const bf16x8*)(Qb + (size_t)(i0 + l15) * DKK + ks * 32 + quad * 8);

    if (tid < 16) { mSt[tid] = -1e30f; lSt[tid] = 0.f; }

    f32x4 accO[4];
    #pragma unroll
    for (int nt = 0; nt < 4; ++nt) accO[nt] = 0;

    for (int j0 = 0; j0 < LL; j0 += 64) {
        // ---- stage K tile [64][256] into LDS, coalesced
        #pragma unroll
        for (int u = 0; u < 8; ++u) {
            int id = u * 256 + tid;
            int jr = id >> 5, ck = id & 31;
            *(bf16x8*)&Klds[jr][ck * 8] =
                *(const bf16x8*)(Kb + (size_t)(j0 + jr) * DKK + ck * 8);
        }
        __syncthreads();                               // b1
        // ---- S = Q·K^T : wave w owns 16-col strip
        f32x4 s0 = 0;
        #pragma unroll
        for (int ks = 0; ks < 8; ++ks) {
            bf16x8 kf = *(const bf16x8*)&Klds[wid * 16 + l15][ks * 32 + quad * 8];
            s0 = __builtin_amdgcn_mfma_f32_16x16x32_bf16(Qreg[ks], kf, s0, 0, 0, 0);
        }
        #pragma unroll
        for (int r = 0; r < 4; ++r)
            Ss[quad * 4 + r][wid * 16 + l15] = s0[r];
        __syncthreads();                               // b2
        // ---- online softmax: 16 threads/row, 4 cols each; Srel added (coalesced)
        {
            int r = tid >> 4, sg = tid & 15;
            int i = i0 + r;
            bf16x4 s4 = *(const bf16x4*)(Sb + (size_t)i * LL + j0 + sg * 4);
            float v[4];
            #pragma unroll
            for (int c = 0; c < 4; ++c) {
                int j = j0 + sg * 4 + c;
                float sr = (j == i + 1) ? 0.f : (float)s4[c];
                v[c] = (Ss[r][sg * 4 + c] + sr) * 0.0625f;
            }
            float tmax = fmaxf(fmaxf(v[0], v[1]), fmaxf(v[2], v[3]));
            tmax = fmaxf(tmax, __shfl_xor(tmax, 1));
            tmax = fmaxf(tmax, __shfl_xor(tmax, 2));
            tmax = fmaxf(tmax, __shfl_xor(tmax, 4));
            tmax = fmaxf(tmax, __shfl_xor(tmax, 8));
            float mOld = mSt[r], lOld = lSt[r];
            float mNew = fmaxf(mOld, tmax);
            float alpha = __expf(mOld - mNew);
            float ps = 0.f;
            bf16x4 pv;
            #pragma unroll
            for (int c = 0; c < 4; ++c) {
                float p = __expf(v[c] - mNew);
                ps += p;
                pv[c] = (bf16)p;
            }
            ps += __shfl_xor(ps, 1);
            ps += __shfl_xor(ps, 2);
            ps += __shfl_xor(ps, 4);
            ps += __shfl_xor(ps, 8);
            *(bf16x4*)&Ps[r][sg * 4] = pv;
            if (sg == 0) { mSt[r] = mNew; lSt[r] = alpha * lOld + ps; aSt[r] = alpha; }
        }
        __syncthreads();                               // b3
        // ---- O = alpha*O + P·V : wave owns 64 d-cols of this block's d-half.
        // (No tail barrier: Klds next-stage writes are separated from this iter's
        //  reads by b2+b3; Ps next writes separated from aF reads by b1'+b2'.)
        bf16x8 aF0 = *(const bf16x8*)&Ps[l15][quad * 8];
        bf16x8 aF1 = *(const bf16x8*)&Ps[l15][32 + quad * 8];
        float ar[4];
        #pragma unroll
        for (int r = 0; r < 4; ++r) ar[r] = aSt[quad * 4 + r];
        const bf16* vbase = Vt + (size_t)(dh * 256 + wid * 64 + l15) * (BB * LL)
                               + (size_t)b * LL + j0 + quad * 8;
        #pragma unroll
        for (int nt = 0; nt < 4; ++nt) {
            const bf16* vp = vbase + (size_t)nt * 16 * (BB * LL);
            bf16x8 bF0 = *(const bf16x8*)(vp);
            bf16x8 bF1 = *(const bf16x8*)(vp + 32);
            f32x4 o = accO[nt];
            o[0] *= ar[0]; o[1] *= ar[1]; o[2] *= ar[2]; o[3] *= ar[3];
            o = __builtin_amdgcn_mfma_f32_16x16x32_bf16(aF0, bF0, o, 0, 0, 0);
            o = __builtin_amdgcn_mfma_f32_16x16x32_bf16(aF1, bF1, o, 0, 0, 0);
            accO[nt] = o;
        }
    }
    // ---- epilogue
    float lr[4];
    #pragma unroll
    for (int r = 0; r < 4; ++r) lr[r] = 1.f / lSt[quad * 4 + r];
    #pragma unroll
    for (int nt = 0; nt < 4; ++nt)
        #pragma unroll
        for (int r = 0; r < 4; ++r) {
            int i = i0 + quad * 4 + r;
            int d = dh * 256 + wid * 64 + nt * 16 + l15;
            out[((size_t)b * LL + i) * DD + d] = accO[nt][r] * lr[r];
        }
}

extern "C" void kernel_launch(void* const* d_in, const int* in_sizes, int n_in,
                              void* d_out, int out_size, void* d_ws, size_t ws_size,
                              hipStream_t stream) {
    const float* inQ = (const float*)d_in[0];
    const float* inK = (const float*)d_in[1];
    const float* inV = (const float*)d_in[2];
    const float* Wq  = (const float*)d_in[3];
    const float* Wk  = (const float*)d_in[4];
    const float* Wv  = (const float*)d_in[5];
    const float* E   = (const float*)d_in[6];
    float* out = (float*)d_out;

    char* ws = (char*)d_ws;
    bf16* Qw   = (bf16*)(ws);                         // 4 MB  [B,L,DK]
    bf16* Kw   = (bf16*)(ws + ((size_t)4  << 20));    // 4 MB  [B,L,DK]
    bf16* Vt   = (bf16*)(ws + ((size_t)8  << 20));    // 8 MB  [D, B*L]
    bf16* SrelW= (bf16*)(ws + ((size_t)16 << 20));    // 32 MB [B,L,L] (skewed)
    bf16* WqT  = (bf16*)(ws + ((size_t)48 << 20));
    bf16* WkT  = (bf16*)(ws + ((size_t)48 << 20) + 262144);
    bf16* WvT  = (bf16*)(ws + ((size_t)48 << 20) + 524288);
    bf16* EbT  = (bf16*)(ws + ((size_t)49 << 20));    // E as bf16 [L][DK]

    transpose_f32_bf16<<<512,  256, 0, stream>>>(Wq, WqT, DD, DKK);
    transpose_f32_bf16<<<512,  256, 0, stream>>>(Wk, WkT, DD, DKK);
    transpose_f32_bf16<<<1024, 256, 0, stream>>>(Wv, WvT, DD, DD);
    {   // E: f32->bf16 identity copy (R=1 => no transpose)
        int n = LL * DKK;
        transpose_f32_bf16<<<(n + 255) / 256, 256, 0, stream>>>(E, EbT, 1, n);
    }

    gemm_bt<1,0><<<dim3(512, 1),  256, 0, stream>>>(inQ, WqT, Qw, BB*LL, DKK, DD, 0, 0, 0, 0);
    gemm_bt<1,0><<<dim3(512, 1),  256, 0, stream>>>(inK, WkT, Kw, BB*LL, DKK, DD, 0, 0, 0, 0);
    gemm_bt<1,0><<<dim3(1024, 1), 256, 0, stream>>>(inV, WvT, Vt, BB*LL, DD, DD, 0, 0, 1, BB*LL);
    gemm_bt<0,1><<<dim3(1024, BB), 256, 0, stream>>>(Qw, EbT, SrelW, LL, LL, DKK,
                                                     (long)LL*DKK, (long)LL*LL, 0, 0);
    attn_kernel<<<dim3(BB * (LL / 16) * 2), 256, 0, stream>>>(Qw, Kw, Vt, SrelW, out);
}

// Round 7
// 291.985 us; speedup vs baseline: 2.0332x; 1.2825x over previous
//
#include <hip/hip_runtime.h>
#include <hip/hip_bf16.h>

#define BB 4
#define LL 2048
#define DD 512
#define DKK 256

typedef __bf16 bf16;
typedef __bf16 bf16x4 __attribute__((ext_vector_type(4)));
typedef __bf16 bf16x8 __attribute__((ext_vector_type(8)));
typedef float f32x4 __attribute__((ext_vector_type(4)));

__device__ __forceinline__ void async_ld16(const bf16* g, bf16* l) {
    __builtin_amdgcn_global_load_lds(
        (const __attribute__((address_space(1))) void*)g,
        (__attribute__((address_space(3))) void*)l, 16, 0, 0);
}

__global__ void transpose_f32_bf16(const float* __restrict__ in, bf16* __restrict__ out,
                                   int R, int C) {
    int idx = blockIdx.x * 256 + threadIdx.x;
    if (idx < R * C) {
        int r = idx / C, c = idx % C;
        out[(size_t)c * R + r] = (bf16)in[idx];
    }
}

// C[m][n] = sum_k A[m][k] * Bt[n][k].  64x64 tile, 4 waves (each 32x32).
template <int AF32, int SKEW>
__global__ void gemm_bt(const void* __restrict__ Av, const bf16* __restrict__ Bt,
                        bf16* __restrict__ C, int M, int N, int K,
                        long aStride, long cStride, int transStore, int ldct)
{
    __shared__ bf16 Als[2][64][40];
    __shared__ bf16 Tls[64][72];

    int tid  = threadIdx.x;
    int lane = tid & 63;
    int wid  = tid >> 6;
    int l15  = lane & 15;
    int quad = lane >> 4;
    int nb = N >> 6;
    int gx = blockIdx.x % nb;
    int gy = blockIdx.x / nb;
    int m0 = gy * 64 + (wid & 1) * 32;
    int n0 = gx * 64 + (wid >> 1) * 32;

    int rowA = tid >> 2;
    int offA = (tid & 3) * 8;

    const float* aPtrF = nullptr;
    const bf16*  aPtrB = nullptr;
    if (AF32) aPtrF = (const float*)Av + (size_t)blockIdx.y * aStride
                      + (size_t)(gy * 64 + rowA) * K + offA;
    else      aPtrB = (const bf16*)Av + (size_t)blockIdx.y * aStride
                      + (size_t)(gy * 64 + rowA) * K + offA;

    const bf16* br0 = Bt + (size_t)(n0 + l15) * K + quad * 8;
    const bf16* br1 = br0 + (size_t)16 * K;

    f32x4 acc00 = 0, acc01 = 0, acc10 = 0, acc11 = 0;

    if (AF32) {
        f32x4 lo = *(const f32x4*)(aPtrF);
        f32x4 hi = *(const f32x4*)(aPtrF + 4);
        bf16x8 pk;
        #pragma unroll
        for (int j = 0; j < 4; ++j) { pk[j] = (bf16)lo[j]; pk[j + 4] = (bf16)hi[j]; }
        *(bf16x8*)&Als[0][rowA][offA] = pk;
    } else {
        *(bf16x8*)&Als[0][rowA][offA] = *(const bf16x8*)(aPtrB);
    }

    int nsteps = K >> 5;
    for (int s = 0; s < nsteps; ++s) {
        __syncthreads();
        if (s + 1 < nsteps) {
            if (AF32) {
                f32x4 lo = *(const f32x4*)(aPtrF + (s + 1) * 32);
                f32x4 hi = *(const f32x4*)(aPtrF + (s + 1) * 32 + 4);
                bf16x8 pk;
                #pragma unroll
                for (int j = 0; j < 4; ++j) { pk[j] = (bf16)lo[j]; pk[j + 4] = (bf16)hi[j]; }
                *(bf16x8*)&Als[(s + 1) & 1][rowA][offA] = pk;
            } else {
                *(bf16x8*)&Als[(s + 1) & 1][rowA][offA] =
                    *(const bf16x8*)(aPtrB + (s + 1) * 32);
            }
        }
        bf16x8 a0 = *(const bf16x8*)&Als[s & 1][(wid & 1) * 32 + l15][quad * 8];
        bf16x8 a1 = *(const bf16x8*)&Als[s & 1][(wid & 1) * 32 + 16 + l15][quad * 8];
        bf16x8 b0 = *(const bf16x8*)(br0 + s * 32);
        bf16x8 b1 = *(const bf16x8*)(br1 + s * 32);
        acc00 = __builtin_amdgcn_mfma_f32_16x16x32_bf16(a0, b0, acc00, 0, 0, 0);
        acc01 = __builtin_amdgcn_mfma_f32_16x16x32_bf16(a0, b1, acc01, 0, 0, 0);
        acc10 = __builtin_amdgcn_mfma_f32_16x16x32_bf16(a1, b0, acc10, 0, 0, 0);
        acc11 = __builtin_amdgcn_mfma_f32_16x16x32_bf16(a1, b1, acc11, 0, 0, 0);
    }

    bf16* Cb = C + (size_t)blockIdx.y * cStride;
    if (SKEW) {
        #pragma unroll
        for (int t = 0; t < 4; ++t) {
            f32x4 av = (t == 0) ? acc00 : (t == 1) ? acc01 : (t == 2) ? acc10 : acc11;
            int ti = t >> 1, tj = t & 1;
            #pragma unroll
            for (int r = 0; r < 4; ++r) {
                int row = m0 + ti * 16 + quad * 4 + r;
                int c   = n0 + tj * 16 + l15;
                bool lower = (c >= LL - 1 - row);
                int dr = lower ? row : row - 1;
                int dc = lower ? c - (LL - 1 - row) : c + row + 1;
                if (lower || row >= 1)
                    Cb[(size_t)dr * LL + dc] = (bf16)av[r];
            }
        }
    } else if (!transStore) {
        #pragma unroll
        for (int t = 0; t < 4; ++t) {
            f32x4 av = (t == 0) ? acc00 : (t == 1) ? acc01 : (t == 2) ? acc10 : acc11;
            int ti = t >> 1, tj = t & 1;
            #pragma unroll
            for (int r = 0; r < 4; ++r) {
                int m = m0 + ti * 16 + quad * 4 + r;
                int n = n0 + tj * 16 + l15;
                Cb[(size_t)m * N + n] = (bf16)av[r];
            }
        }
    } else {
        int mW = (wid & 1) * 32, nW = (wid >> 1) * 32;
        __syncthreads();
        #pragma unroll
        for (int t = 0; t < 4; ++t) {
            f32x4 av = (t == 0) ? acc00 : (t == 1) ? acc01 : (t == 2) ? acc10 : acc11;
            int ti = t >> 1, tj = t & 1;
            int nL  = nW + tj * 16 + l15;
            int mL0 = mW + ti * 16 + quad * 4;
            bf16x4 pk;
            #pragma unroll
            for (int r = 0; r < 4; ++r) pk[r] = (bf16)av[r];
            *(bf16x4*)&Tls[nL][mL0] = pk;
        }
        __syncthreads();
        int r = tid >> 2, c = tid & 3;
        bf16x8 v0 = *(const bf16x8*)&Tls[r][c * 16];
        bf16x8 v1 = *(const bf16x8*)&Tls[r][c * 16 + 8];
        bf16* dst = Cb + (size_t)(gx * 64 + r) * ldct + gy * 64 + c * 16;
        *(bf16x8*)dst = v0;
        *(bf16x8*)(dst + 8) = v1;
    }
}

// Fused attention v3: BM=32 rows, d-half per block (512 blocks, 2/CU, 8 waves/CU).
// K-tile AND V-tile staged direct-to-LDS via global_load_lds (16B), with
// rotation swizzle (chunk c of row r at (c+r)&mask) so all b128 frag reads are
// bank-balanced.  Q in registers.  All accO loops fully unrolled (R3 lesson).
__launch_bounds__(256, 2)
__global__ void attn_kernel(const bf16* __restrict__ Qw, const bf16* __restrict__ Kw,
                            const bf16* __restrict__ Vt, const bf16* __restrict__ Srel,
                            float* __restrict__ out)
{
    __shared__ bf16  Klds[64 * 256];      // rows j (64), 32 chunks of 8, rotated
    __shared__ bf16  Vlds[256 * 64];      // rows d (256), 8 chunks of 8, rotated
    __shared__ float Ss[32][68];          // pitch 272B: 16B-aligned rows
    __shared__ bf16  Ps[32][72];          // pitch 144B: 16B mult, bank-balanced
    __shared__ float mSt[32], lSt[32], aSt[32];

    int tid  = threadIdx.x;
    int lane = tid & 63;
    int wid  = tid >> 6;
    int l15  = lane & 15;
    int quad = lane >> 4;

    int dh = blockIdx.x & 1;
    int it = (blockIdx.x >> 1) & 63;
    int b  = blockIdx.x >> 7;
    int i0 = it * 32;

    const bf16* Qb = Qw + (size_t)b * LL * DKK;
    const bf16* Kb = Kw + (size_t)b * LL * DKK;
    const bf16* Sb = Srel + (size_t)b * LL * LL;
    const bf16* Vb = Vt + (size_t)(dh * 256) * (BB * LL) + (size_t)b * LL;

    // Q fragments in registers (one-time): rows i0 + rt*16 + l15
    bf16x8 Qreg[2][8];
    #pragma unroll
    for (int rt = 0; rt < 2; ++rt)
        #pragma unroll
        for (int ks = 0; ks < 8; ++ks)
            Qreg[rt][ks] = *(const bf16x8*)(Qb + (size_t)(i0 + rt * 16 + l15) * DKK
                                            + ks * 32 + quad * 8);

    if (tid < 32) { mSt[tid] = -1e30f; lSt[tid] = 0.f; }

    f32x4 accO[2][4];
    #pragma unroll
    for (int rt = 0; rt < 2; ++rt)
        #pragma unroll
        for (int nt = 0; nt < 4; ++nt) accO[rt][nt] = 0;

    for (int j0 = 0; j0 < LL; j0 += 64) {
        // ---- stage K tile [64 j][256 k] : 32 wave-insts, rotated chunks
        #pragma unroll
        for (int u = 0; u < 8; ++u) {
            int inst = wid * 8 + u;
            int s = inst * 64 + lane;
            int j = s >> 5, cp = lane & 31;
            int c = (cp - j) & 31;
            async_ld16(Kb + (size_t)(j0 + j) * DKK + c * 8, Klds + inst * 512);
        }
        // ---- stage V tile [256 d][64 j] : 32 wave-insts, rotated chunks
        #pragma unroll
        for (int u = 0; u < 8; ++u) {
            int inst = wid * 8 + u;
            int s = inst * 64 + lane;
            int d = s >> 3, cp = lane & 7;
            int c = (cp - d) & 7;
            async_ld16(Vb + (size_t)d * (BB * LL) + j0 + c * 8, Vlds + inst * 512);
        }
        __syncthreads();                                    // b1 (drains vmcnt)
        // ---- S = Q·K^T : wave w owns 16-col strip, both row-tiles
        {
            f32x4 s0 = 0, s1 = 0;
            int jrow = wid * 16 + l15;
            #pragma unroll
            for (int ks = 0; ks < 8; ++ks) {
                int c = ks * 4 + quad;
                int cp = (c + jrow) & 31;
                bf16x8 kf = *(const bf16x8*)&Klds[jrow * 256 + cp * 8];
                s0 = __builtin_amdgcn_mfma_f32_16x16x32_bf16(Qreg[0][ks], kf, s0, 0, 0, 0);
                s1 = __builtin_amdgcn_mfma_f32_16x16x32_bf16(Qreg[1][ks], kf, s1, 0, 0, 0);
            }
            #pragma unroll
            for (int r = 0; r < 4; ++r) {
                Ss[quad * 4 + r][wid * 16 + l15]      = s0[r];
                Ss[16 + quad * 4 + r][wid * 16 + l15] = s1[r];
            }
        }
        __syncthreads();                                    // b2
        // ---- online softmax: 8 threads/row; Srel added (coalesced 16B loads)
        {
            int r = tid >> 3, sg = tid & 7;
            int i = i0 + r;
            bf16x8 s8 = *(const bf16x8*)(Sb + (size_t)i * LL + j0 + sg * 8);
            float v[8];
            #pragma unroll
            for (int c = 0; c < 8; ++c) {
                float sr = (j0 + sg * 8 + c == i + 1) ? 0.f : (float)s8[c];
                v[c] = (Ss[r][sg * 8 + c] + sr) * 0.0625f;
            }
            float tmax = v[0];
            #pragma unroll
            for (int c = 1; c < 8; ++c) tmax = fmaxf(tmax, v[c]);
            tmax = fmaxf(tmax, __shfl_xor(tmax, 1));
            tmax = fmaxf(tmax, __shfl_xor(tmax, 2));
            tmax = fmaxf(tmax, __shfl_xor(tmax, 4));
            float mOld = mSt[r], lOld = lSt[r];
            float mNew = fmaxf(mOld, tmax);
            float alpha = __expf(mOld - mNew);
            float ps = 0.f;
            bf16x8 pv;
            #pragma unroll
            for (int c = 0; c < 8; ++c) {
                float p = __expf(v[c] - mNew);
                ps += p;
                pv[c] = (bf16)p;
            }
            ps += __shfl_xor(ps, 1);
            ps += __shfl_xor(ps, 2);
            ps += __shfl_xor(ps, 4);
            *(bf16x8*)&Ps[r][sg * 8] = pv;
            if (sg == 0) { mSt[r] = mNew; lSt[r] = alpha * lOld + ps; aSt[r] = alpha; }
        }
        __syncthreads();                                    // b3
        // ---- O = alpha*O + P·V : wave owns 64 d-cols (within block's half)
        {
            bf16x8 aF[2][2];
            #pragma unroll
            for (int rt = 0; rt < 2; ++rt)
                #pragma unroll
                for (int kk = 0; kk < 2; ++kk)
                    aF[rt][kk] = *(const bf16x8*)&Ps[rt * 16 + l15][kk * 32 + quad * 8];
            float ar[2][4];
            #pragma unroll
            for (int rt = 0; rt < 2; ++rt)
                #pragma unroll
                for (int r = 0; r < 4; ++r) ar[rt][r] = aSt[rt * 16 + quad * 4 + r];
            #pragma unroll
            for (int nt = 0; nt < 4; ++nt) {
                int dd = wid * 64 + nt * 16 + l15;
                int c0 = (0 * 4 + quad + dd) & 7;
                int c1 = (1 * 4 + quad + dd) & 7;
                bf16x8 bF0 = *(const bf16x8*)&Vlds[dd * 64 + c0 * 8];
                bf16x8 bF1 = *(const bf16x8*)&Vlds[dd * 64 + c1 * 8];
                #pragma unroll
                for (int rt = 0; rt < 2; ++rt) {
                    f32x4 o = accO[rt][nt];
                    o[0] *= ar[rt][0]; o[1] *= ar[rt][1];
                    o[2] *= ar[rt][2]; o[3] *= ar[rt][3];
                    o = __builtin_amdgcn_mfma_f32_16x16x32_bf16(aF[rt][0], bF0, o, 0, 0, 0);
                    o = __builtin_amdgcn_mfma_f32_16x16x32_bf16(aF[rt][1], bF1, o, 0, 0, 0);
                    accO[rt][nt] = o;
                }
            }
        }
        __syncthreads();                                    // b4 (Klds/Vlds reuse)
    }
    // ---- epilogue
    float lr[2][4];
    #pragma unroll
    for (int rt = 0; rt < 2; ++rt)
        #pragma unroll
        for (int r = 0; r < 4; ++r) lr[rt][r] = 1.f / lSt[rt * 16 + quad * 4 + r];
    #pragma unroll
    for (int rt = 0; rt < 2; ++rt)
        #pragma unroll
        for (int nt = 0; nt < 4; ++nt)
            #pragma unroll
            for (int r = 0; r < 4; ++r) {
                int i = i0 + rt * 16 + quad * 4 + r;
                int d = dh * 256 + wid * 64 + nt * 16 + l15;
                out[((size_t)b * LL + i) * DD + d] = accO[rt][nt][r] * lr[rt][r];
            }
}

extern "C" void kernel_launch(void* const* d_in, const int* in_sizes, int n_in,
                              void* d_out, int out_size, void* d_ws, size_t ws_size,
                              hipStream_t stream) {
    const float* inQ = (const float*)d_in[0];
    const float* inK = (const float*)d_in[1];
    const float* inV = (const float*)d_in[2];
    const float* Wq  = (const float*)d_in[3];
    const float* Wk  = (const float*)d_in[4];
    const float* Wv  = (const float*)d_in[5];
    const float* E   = (const float*)d_in[6];
    float* out = (float*)d_out;

    char* ws = (char*)d_ws;
    bf16* Qw   = (bf16*)(ws);                         // 4 MB  [B,L,DK]
    bf16* Kw   = (bf16*)(ws + ((size_t)4  << 20));    // 4 MB  [B,L,DK]
    bf16* Vt   = (bf16*)(ws + ((size_t)8  << 20));    // 8 MB  [D, B*L]
    bf16* SrelW= (bf16*)(ws + ((size_t)16 << 20));    // 32 MB [B,L,L] (skewed)
    bf16* WqT  = (bf16*)(ws + ((size_t)48 << 20));
    bf16* WkT  = (bf16*)(ws + ((size_t)48 << 20) + 262144);
    bf16* WvT  = (bf16*)(ws + ((size_t)48 << 20) + 524288);
    bf16* EbT  = (bf16*)(ws + ((size_t)49 << 20));

    transpose_f32_bf16<<<512,  256, 0, stream>>>(Wq, WqT, DD, DKK);
    transpose_f32_bf16<<<512,  256, 0, stream>>>(Wk, WkT, DD, DKK);
    transpose_f32_bf16<<<1024, 256, 0, stream>>>(Wv, WvT, DD, DD);
    {
        int n = LL * DKK;
        transpose_f32_bf16<<<(n + 255) / 256, 256, 0, stream>>>(E, EbT, 1, n);
    }

    gemm_bt<1,0><<<dim3(512, 1),  256, 0, stream>>>(inQ, WqT, Qw, BB*LL, DKK, DD, 0, 0, 0, 0);
    gemm_bt<1,0><<<dim3(512, 1),  256, 0, stream>>>(inK, WkT, Kw, BB*LL, DKK, DD, 0, 0, 0, 0);
    gemm_bt<1,0><<<dim3(1024, 1), 256, 0, stream>>>(inV, WvT, Vt, BB*LL, DD, DD, 0, 0, 1, BB*LL);
    gemm_bt<0,1><<<dim3(1024, BB), 256, 0, stream>>>(Qw, EbT, SrelW, LL, LL, DKK,
                                                     (long)LL*DKK, (long)LL*LL, 0, 0);
    attn_kernel<<<dim3(BB * 64 * 2), 256, 0, stream>>>(Qw, Kw, Vt, SrelW, out);
}

// Round 8
// 264.631 us; speedup vs baseline: 2.2434x; 1.1034x over previous
//
#include <hip/hip_runtime.h>
#include <hip/hip_bf16.h>

#define BB 4
#define LL 2048
#define DD 512
#define DKK 256

typedef __bf16 bf16;
typedef __bf16 bf16x4 __attribute__((ext_vector_type(4)));
typedef __bf16 bf16x8 __attribute__((ext_vector_type(8)));
typedef float f32x4 __attribute__((ext_vector_type(4)));

__device__ __forceinline__ void async_ld16(const bf16* g, bf16* l) {
    __builtin_amdgcn_global_load_lds(
        (const __attribute__((address_space(1))) void*)g,
        (__attribute__((address_space(3))) void*)l, 16, 0, 0);
}

__global__ void conv_f32_bf16v(const float* __restrict__ in, bf16* __restrict__ out, int n4) {
    int i = blockIdx.x * 256 + threadIdx.x;
    if (i < n4) {
        f32x4 v = *(const f32x4*)(in + (size_t)i * 4);
        bf16x4 o;
        #pragma unroll
        for (int j = 0; j < 4; ++j) o[j] = (bf16)v[j];
        *(bf16x4*)(out + (size_t)i * 4) = o;
    }
}

__global__ void transpose_f32_bf16(const float* __restrict__ in, bf16* __restrict__ out,
                                   int R, int C) {
    int idx = blockIdx.x * 256 + threadIdx.x;
    if (idx < R * C) {
        int r = idx / C, c = idx % C;
        out[(size_t)c * R + r] = (bf16)in[idx];
    }
}

// 64x64-tile bf16 transpose: in [R][C] -> out [C][R], coalesced both sides.
__global__ void transpose_bf16_tile(const bf16* __restrict__ in, bf16* __restrict__ out,
                                    int R, int C) {
    __shared__ bf16 t[64][72];
    int tcx = C >> 6;
    int bx = blockIdx.x % tcx, by = blockIdx.x / tcx;
    int r = threadIdx.x >> 2, cc = (threadIdx.x & 3) * 16;
    const bf16* src = in + (size_t)(by * 64 + r) * C + bx * 64 + cc;
    bf16x8 v0 = *(const bf16x8*)src;
    bf16x8 v1 = *(const bf16x8*)(src + 8);
    #pragma unroll
    for (int u = 0; u < 8; ++u) { t[cc + u][r] = v0[u]; t[cc + 8 + u][r] = v1[u]; }
    __syncthreads();
    bf16* dst = out + (size_t)(bx * 64 + r) * R + by * 64 + cc;
    *(bf16x8*)dst = *(const bf16x8*)&t[r][cc];
    *(bf16x8*)(dst + 8) = *(const bf16x8*)&t[r][cc + 8];
}

// Unified bf16 GEMM, m97-style: C[m][n] = sum_k A[m][k]*B[n][k].  128x128 tile,
// 4 waves (each 64x64 = 4x4 acc).  A and B staged direct-to-LDS via
// global_load_lds(16B) with parity-rotation swizzle: chunk c of row r stored at
// slot (c + (r>>1))&3 -> frag reads hit 8 slot-parity combos = 2 lanes/bank (free).
// SKEW=1: scatter-store into skewed Srel layout:
//   QE[r][c] -> (c >= L-1-r) ? Srel[r][c-(L-1-r)] : (r>=1 ? Srel[r-1][c+r+1] : drop)
template <int SKEW>
__launch_bounds__(256, 2)
__global__ void gemm128(const bf16* __restrict__ A, const bf16* __restrict__ B,
                        bf16* __restrict__ C, int N, int K,
                        long aStride, long cStride)
{
    __shared__ bf16 Als[128 * 32];
    __shared__ bf16 Bls[128 * 32];

    int tid  = threadIdx.x;
    int lane = tid & 63;
    int wid  = tid >> 6;
    int l15  = lane & 15;
    int quad = lane >> 4;
    int nb = N >> 7;
    int gx = blockIdx.x % nb;
    int gy = blockIdx.x / nb;

    const bf16* Ab = A + (size_t)blockIdx.y * aStride + (size_t)gy * 128 * K;
    const bf16* Bb = B + (size_t)gx * 128 * K;

    int rl = lane >> 2;     // staging: row within 16-row inst
    int sl = lane & 3;      // staging: slot
    int half = wid & 1;     // waves 0/2: rows 0-63; waves 1/3: rows 64-127
    const bf16* gsrc = (wid < 2) ? Ab : Bb;
    bf16* ldst = (wid < 2) ? Als : Bls;

    f32x4 acc[4][4];
    #pragma unroll
    for (int i = 0; i < 4; ++i)
        #pragma unroll
        for (int j = 0; j < 4; ++j) acc[i][j] = 0;

    for (int k0 = 0; k0 < K; k0 += 32) {
        #pragma unroll
        for (int u = 0; u < 4; ++u) {
            int inst = half * 4 + u;
            int row  = inst * 16 + rl;
            int c    = (sl - (row >> 1)) & 3;
            async_ld16(gsrc + (size_t)row * K + k0 + c * 8, ldst + inst * 512);
        }
        __syncthreads();   // drains vmcnt(0): staging complete
        bf16x8 fA[4], fB[4];
        #pragma unroll
        for (int rt = 0; rt < 4; ++rt) {
            int row = (wid & 1) * 64 + rt * 16 + l15;
            int s   = (quad + (row >> 1)) & 3;
            fA[rt] = *(const bf16x8*)&Als[row * 32 + s * 8];
        }
        #pragma unroll
        for (int ct = 0; ct < 4; ++ct) {
            int col = (wid >> 1) * 64 + ct * 16 + l15;
            int s   = (quad + (col >> 1)) & 3;
            fB[ct] = *(const bf16x8*)&Bls[col * 32 + s * 8];
        }
        #pragma unroll
        for (int rt = 0; rt < 4; ++rt)
            #pragma unroll
            for (int ct = 0; ct < 4; ++ct)
                acc[rt][ct] = __builtin_amdgcn_mfma_f32_16x16x32_bf16(
                                  fA[rt], fB[ct], acc[rt][ct], 0, 0, 0);
        __syncthreads();   // LDS reuse guard
    }

    bf16* Cb = C + (size_t)blockIdx.y * cStride;
    int m0 = gy * 128 + (wid & 1) * 64;
    int n0 = gx * 128 + (wid >> 1) * 64;
    if (!SKEW) {
        #pragma unroll
        for (int rt = 0; rt < 4; ++rt)
            #pragma unroll
            for (int ct = 0; ct < 4; ++ct)
                #pragma unroll
                for (int r = 0; r < 4; ++r) {
                    int m = m0 + rt * 16 + quad * 4 + r;
                    int n = n0 + ct * 16 + l15;
                    Cb[(size_t)m * N + n] = (bf16)acc[rt][ct][r];
                }
    } else {
        #pragma unroll
        for (int rt = 0; rt < 4; ++rt)
            #pragma unroll
            for (int ct = 0; ct < 4; ++ct)
                #pragma unroll
                for (int r = 0; r < 4; ++r) {
                    int row = m0 + rt * 16 + quad * 4 + r;
                    int c   = n0 + ct * 16 + l15;
                    bool lower = (c >= LL - 1 - row);
                    int dr = lower ? row : row - 1;
                    int dc = lower ? c - (LL - 1 - row) : c + row + 1;
                    if (lower || row >= 1)
                        Cb[(size_t)dr * LL + dc] = (bf16)acc[rt][ct][r];
                }
    }
}

// Fused attention (R7 structure) + XCD pinning: blockIdx%8 selects (b,dh) so the
// 64 blocks sharing one K[b] (1MB) + V-half (1MB) land on one XCD -> staged K/V
// stay resident in that XCD's 4MB L2 (cross-XCD L2s aren't shared).
// All accO loops fully unrolled (R3: dynamic index => scratch spill).
__launch_bounds__(256, 2)
__global__ void attn_kernel(const bf16* __restrict__ Qw, const bf16* __restrict__ Kw,
                            const bf16* __restrict__ Vt, const bf16* __restrict__ Srel,
                            float* __restrict__ out)
{
    __shared__ bf16  Klds[64 * 256];      // rows j (64), 32 chunks of 8, rotated
    __shared__ bf16  Vlds[256 * 64];      // rows d (256), 8 chunks of 8, rotated
    __shared__ float Ss[32][68];
    __shared__ bf16  Ps[32][72];
    __shared__ float mSt[32], lSt[32], aSt[32];

    int tid  = threadIdx.x;
    int lane = tid & 63;
    int wid  = tid >> 6;
    int l15  = lane & 15;
    int quad = lane >> 4;

    int xcd = blockIdx.x & 7;          // XCD = blockIdx % 8 (round-robin dispatch)
    int b   = xcd >> 1;
    int dh  = xcd & 1;
    int i0  = (blockIdx.x >> 3) * 32;

    const bf16* Qb = Qw + (size_t)b * LL * DKK;
    const bf16* Kb = Kw + (size_t)b * LL * DKK;
    const bf16* Sb = Srel + (size_t)b * LL * LL;
    const bf16* Vb = Vt + (size_t)(dh * 256) * (BB * LL) + (size_t)b * LL;

    bf16x8 Qreg[2][8];
    #pragma unroll
    for (int rt = 0; rt < 2; ++rt)
        #pragma unroll
        for (int ks = 0; ks < 8; ++ks)
            Qreg[rt][ks] = *(const bf16x8*)(Qb + (size_t)(i0 + rt * 16 + l15) * DKK
                                            + ks * 32 + quad * 8);

    if (tid < 32) { mSt[tid] = -1e30f; lSt[tid] = 0.f; }

    f32x4 accO[2][4];
    #pragma unroll
    for (int rt = 0; rt < 2; ++rt)
        #pragma unroll
        for (int nt = 0; nt < 4; ++nt) accO[rt][nt] = 0;

    for (int j0 = 0; j0 < LL; j0 += 64) {
        #pragma unroll
        for (int u = 0; u < 8; ++u) {
            int inst = wid * 8 + u;
            int s = inst * 64 + lane;
            int j = s >> 5, cp = lane & 31;
            int c = (cp - j) & 31;
            async_ld16(Kb + (size_t)(j0 + j) * DKK + c * 8, Klds + inst * 512);
        }
        #pragma unroll
        for (int u = 0; u < 8; ++u) {
            int inst = wid * 8 + u;
            int s = inst * 64 + lane;
            int d = s >> 3, cp = lane & 7;
            int c = (cp - d) & 7;
            async_ld16(Vb + (size_t)d * (BB * LL) + j0 + c * 8, Vlds + inst * 512);
        }
        __syncthreads();                                    // b1
        {
            f32x4 s0 = 0, s1 = 0;
            int jrow = wid * 16 + l15;
            #pragma unroll
            for (int ks = 0; ks < 8; ++ks) {
                int c = ks * 4 + quad;
                int cp = (c + jrow) & 31;
                bf16x8 kf = *(const bf16x8*)&Klds[jrow * 256 + cp * 8];
                s0 = __builtin_amdgcn_mfma_f32_16x16x32_bf16(Qreg[0][ks], kf, s0, 0, 0, 0);
                s1 = __builtin_amdgcn_mfma_f32_16x16x32_bf16(Qreg[1][ks], kf, s1, 0, 0, 0);
            }
            #pragma unroll
            for (int r = 0; r < 4; ++r) {
                Ss[quad * 4 + r][wid * 16 + l15]      = s0[r];
                Ss[16 + quad * 4 + r][wid * 16 + l15] = s1[r];
            }
        }
        __syncthreads();                                    // b2
        {
            int r = tid >> 3, sg = tid & 7;
            int i = i0 + r;
            bf16x8 s8 = *(const bf16x8*)(Sb + (size_t)i * LL + j0 + sg * 8);
            float v[8];
            #pragma unroll
            for (int c = 0; c < 8; ++c) {
                float sr = (j0 + sg * 8 + c == i + 1) ? 0.f : (float)s8[c];
                v[c] = (Ss[r][sg * 8 + c] + sr) * 0.0625f;
            }
            float tmax = v[0];
            #pragma unroll
            for (int c = 1; c < 8; ++c) tmax = fmaxf(tmax, v[c]);
            tmax = fmaxf(tmax, __shfl_xor(tmax, 1));
            tmax = fmaxf(tmax, __shfl_xor(tmax, 2));
            tmax = fmaxf(tmax, __shfl_xor(tmax, 4));
            float mOld = mSt[r], lOld = lSt[r];
            float mNew = fmaxf(mOld, tmax);
            float alpha = __expf(mOld - mNew);
            float ps = 0.f;
            bf16x8 pv;
            #pragma unroll
            for (int c = 0; c < 8; ++c) {
                float p = __expf(v[c] - mNew);
                ps += p;
                pv[c] = (bf16)p;
            }
            ps += __shfl_xor(ps, 1);
            ps += __shfl_xor(ps, 2);
            ps += __shfl_xor(ps, 4);
            *(bf16x8*)&Ps[r][sg * 8] = pv;
            if (sg == 0) { mSt[r] = mNew; lSt[r] = alpha * lOld + ps; aSt[r] = alpha; }
        }
        __syncthreads();                                    // b3
        {
            bf16x8 aF[2][2];
            #pragma unroll
            for (int rt = 0; rt < 2; ++rt)
                #pragma unroll
                for (int kk = 0; kk < 2; ++kk)
                    aF[rt][kk] = *(const bf16x8*)&Ps[rt * 16 + l15][kk * 32 + quad * 8];
            float ar[2][4];
            #pragma unroll
            for (int rt = 0; rt < 2; ++rt)
                #pragma unroll
                for (int r = 0; r < 4; ++r) ar[rt][r] = aSt[rt * 16 + quad * 4 + r];
            #pragma unroll
            for (int nt = 0; nt < 4; ++nt) {
                int dd = wid * 64 + nt * 16 + l15;
                int c0 = (0 * 4 + quad + dd) & 7;
                int c1 = (1 * 4 + quad + dd) & 7;
                bf16x8 bF0 = *(const bf16x8*)&Vlds[dd * 64 + c0 * 8];
                bf16x8 bF1 = *(const bf16x8*)&Vlds[dd * 64 + c1 * 8];
                #pragma unroll
                for (int rt = 0; rt < 2; ++rt) {
                    f32x4 o = accO[rt][nt];
                    o[0] *= ar[rt][0]; o[1] *= ar[rt][1];
                    o[2] *= ar[rt][2]; o[3] *= ar[rt][3];
                    o = __builtin_amdgcn_mfma_f32_16x16x32_bf16(aF[rt][0], bF0, o, 0, 0, 0);
                    o = __builtin_amdgcn_mfma_f32_16x16x32_bf16(aF[rt][1], bF1, o, 0, 0, 0);
                    accO[rt][nt] = o;
                }
            }
        }
        __syncthreads();                                    // b4
    }
    float lr[2][4];
    #pragma unroll
    for (int rt = 0; rt < 2; ++rt)
        #pragma unroll
        for (int r = 0; r < 4; ++r) lr[rt][r] = 1.f / lSt[rt * 16 + quad * 4 + r];
    #pragma unroll
    for (int rt = 0; rt < 2; ++rt)
        #pragma unroll
        for (int nt = 0; nt < 4; ++nt)
            #pragma unroll
            for (int r = 0; r < 4; ++r) {
                int i = i0 + rt * 16 + quad * 4 + r;
                int d = dh * 256 + wid * 64 + nt * 16 + l15;
                out[((size_t)b * LL + i) * DD + d] = accO[rt][nt][r] * lr[rt][r];
            }
}

extern "C" void kernel_launch(void* const* d_in, const int* in_sizes, int n_in,
                              void* d_out, int out_size, void* d_ws, size_t ws_size,
                              hipStream_t stream) {
    const float* inQ = (const float*)d_in[0];
    const float* inK = (const float*)d_in[1];
    const float* inV = (const float*)d_in[2];
    const float* Wq  = (const float*)d_in[3];
    const float* Wk  = (const float*)d_in[4];
    const float* Wv  = (const float*)d_in[5];
    const float* E   = (const float*)d_in[6];
    float* out = (float*)d_out;

    char* ws = (char*)d_ws;
    bf16* Qw   = (bf16*)(ws);                         // 4 MB  [B*L][DK]
    bf16* Kw   = (bf16*)(ws + ((size_t)4  << 20));    // 4 MB  [B*L][DK]
    bf16* Vt   = (bf16*)(ws + ((size_t)8  << 20));    // 8 MB  [D][B*L]
    bf16* SrelW= (bf16*)(ws + ((size_t)16 << 20));    // 32 MB [B,L,L] skewed
    // transient buffers inside the Srel region (dead before QE writes Srel):
    bf16* Xq   = (bf16*)(ws + ((size_t)16 << 20));    // 8 MB  inQ as bf16
    bf16* Xk   = (bf16*)(ws + ((size_t)24 << 20));    // 8 MB
    bf16* Xv   = (bf16*)(ws + ((size_t)32 << 20));    // 8 MB
    bf16* Vw   = (bf16*)(ws + ((size_t)40 << 20));    // 8 MB  V row-major
    bf16* WqT  = (bf16*)(ws + ((size_t)48 << 20));            // [DK][D]
    bf16* WkT  = (bf16*)(ws + ((size_t)48 << 20) + 262144);   // [DK][D]
    bf16* WvT  = (bf16*)(ws + ((size_t)48 << 20) + 524288);   // [D][D]
    bf16* Eb   = (bf16*)(ws + ((size_t)49 << 20));            // [L][DK]

    conv_f32_bf16v<<<4096, 256, 0, stream>>>(inQ, Xq, (BB * LL * DD) / 4);
    conv_f32_bf16v<<<4096, 256, 0, stream>>>(inK, Xk, (BB * LL * DD) / 4);
    conv_f32_bf16v<<<4096, 256, 0, stream>>>(inV, Xv, (BB * LL * DD) / 4);
    conv_f32_bf16v<<<512,  256, 0, stream>>>(E, Eb, (LL * DKK) / 4);
    transpose_f32_bf16<<<512,  256, 0, stream>>>(Wq, WqT, DD, DKK);
    transpose_f32_bf16<<<512,  256, 0, stream>>>(Wk, WkT, DD, DKK);
    transpose_f32_bf16<<<1024, 256, 0, stream>>>(Wv, WvT, DD, DD);

    // Q = Xq·Wq^T': M=8192 N=256 K=512
    gemm128<0><<<dim3(2 * 64, 1),  256, 0, stream>>>(Xq, WqT, Qw, DKK, DD, 0, 0);
    gemm128<0><<<dim3(2 * 64, 1),  256, 0, stream>>>(Xk, WkT, Kw, DKK, DD, 0, 0);
    // Vw = Xv·Wv^T': M=8192 N=512 K=512
    gemm128<0><<<dim3(4 * 64, 1),  256, 0, stream>>>(Xv, WvT, Vw, DD, DD, 0, 0);
    // Vt = Vw^T  [512][8192]
    transpose_bf16_tile<<<(DD / 64) * (BB * LL / 64), 256, 0, stream>>>(Vw, Vt, BB * LL, DD);
    // Srel (skewed) = skew(Q·E^T): per-batch M=N=2048 K=256
    gemm128<1><<<dim3(16 * 16, BB), 256, 0, stream>>>(Qw, Eb, SrelW, LL, DKK,
                                                      (long)LL * DKK, (long)LL * LL);
    attn_kernel<<<dim3(BB * 64 * 2), 256, 0, stream>>>(Qw, Kw, Vt, SrelW, out);
}